// Round 13
// baseline (148.125 us; speedup 1.0000x reference)
//
#include <hip/hip_runtime.h>
#include <math.h>

// ---------------- types ----------------
typedef __attribute__((ext_vector_type(8)))  __bf16 bf16x8;
typedef __attribute__((ext_vector_type(4)))  float  f32x4;
typedef __attribute__((ext_vector_type(4)))  unsigned short ushort4v;
typedef __attribute__((ext_vector_type(8)))  unsigned short ushort8v;

#define MFMA16(acc, a, b) acc = __builtin_amdgcn_mfma_f32_16x16x32_bf16((a),(b),(acc),0,0,0)

__device__ inline unsigned short f2b(float f) {
    __bf16 b = (__bf16)f;                      // native RNE cvt (single op)
    union { __bf16 b; unsigned short u; } v; v.b = b;
    return v.u;
}
__device__ inline float b2f(unsigned short h) {
    union { unsigned int u; float f; } v; v.u = ((unsigned int)h) << 16;
    return v.f;
}
__device__ inline float fast_rcp(float x) { return __builtin_amdgcn_rcpf(x); }
__device__ inline float tanh_fast(float z) {
    float e = __expf(2.0f * z);
    return 1.0f - 2.0f * fast_rcp(e + 1.0f);   // rcp instead of precise div
}
__device__ inline float gelu_g(float x) {
    const float c0 = 0.7978845608028654f, c1 = 0.044715f;
    float z = c0 * x * (1.0f + c1 * x * x);
    return 0.5f * x * (1.0f + tanh_fast(z));
}
__device__ inline void gelu_both(float x, float& g, float& gp) {
    const float c0 = 0.7978845608028654f, c1 = 0.044715f;
    float x2 = x * x;
    float z  = c0 * x * (1.0f + c1 * x2);
    float t  = tanh_fast(z);
    g  = 0.5f * x * (1.0f + t);
    float dz = c0 * (1.0f + 3.0f * c1 * x2);
    gp = 0.5f * (1.0f + t) + 0.5f * x * (1.0f - t * t) * dz;
}
__device__ inline float sigmoidf(float x) { return fast_rcp(1.0f + __expf(-x)); }

// ---------------- weight prep: bf16 converts + transposes ----------------
__global__ __launch_bounds__(256) void k_wprep(
    const float* __restrict__ Wk, const float* __restrict__ Wv,
    const float* __restrict__ w0_g, const float* __restrict__ w1_g,
    const float* __restrict__ nw_g,
    unsigned short* __restrict__ WkvT, unsigned short* __restrict__ w0fT,
    unsigned short* __restrict__ w1T, unsigned short* __restrict__ w0N,
    unsigned short* __restrict__ w1N)
{
    const int bid = blockIdx.x, tid = threadIdx.x;
    __shared__ float tile[64][65];
    if (bid < 128) {
        int kt = bid >> 4, nt = bid & 15;
        const float* src = (nt < 8) ? Wk : Wv;
        int ncol0 = (nt & 7) * 64;
        for (int ii = 0; ii < 16; ++ii) {
            int idx = tid + ii * 256; int r = idx >> 6, cc = idx & 63;
            tile[r][cc] = src[(size_t)(kt * 64 + r) * 512 + ncol0 + cc];
        }
        __syncthreads();
        for (int ii = 0; ii < 16; ++ii) {
            int idx = tid + ii * 256; int r = idx >> 6, cc = idx & 63;
            WkvT[(size_t)(nt * 64 + r) * 512 + kt * 64 + cc] = f2b(tile[cc][r]);
        }
    } else if (bid < 160) {
        int q = bid - 128; int hh = q >> 2, it = q & 3;
        const float* w0h = w0_g + hh * 16384;
        for (int ii = 0; ii < 16; ++ii) {
            int idx = tid + ii * 256; int r = idx >> 6, cc = idx & 63;
            tile[r][cc] = w0h[r * 256 + it * 64 + cc];
        }
        __syncthreads();
        for (int ii = 0; ii < 16; ++ii) {
            int idx = tid + ii * 256; int r = idx >> 6, cc = idx & 63;
            w0fT[hh * 16384 + (it * 64 + r) * 64 + cc] = f2b(nw_g[hh * 64 + cc] * tile[cc][r]);
        }
    } else if (bid < 192) {
        int q = bid - 160; int hh = q >> 2, it = q & 3;
        const float* w1h = w1_g + hh * 16384;
        for (int ii = 0; ii < 16; ++ii) {
            int idx = tid + ii * 256; int r = idx >> 6, cc = idx & 63;
            tile[r][cc] = w1h[(it * 64 + r) * 64 + cc];
        }
        __syncthreads();
        for (int ii = 0; ii < 16; ++ii) {
            int idx = tid + ii * 256; int r = idx >> 6, cc = idx & 63;
            w1T[hh * 16384 + r * 256 + it * 64 + cc] = f2b(tile[cc][r]);
        }
    } else {
        int q = bid - 192;
        int gid = q * 2048 + tid * 8;
        const float* s; unsigned short* d;
        if (gid < 131072) { s = w0_g + gid; d = w0N + gid; }
        else              { s = w1_g + (gid - 131072); d = w1N + (gid - 131072); }
        #pragma unroll
        for (int jj = 0; jj < 8; ++jj) d[jj] = f2b(s[jj]);
    }
}

// ---------------- rmsnorm(seq)->xb(bf16)  +  lr projection (fused) --------
__global__ __launch_bounds__(256) void k_rms_lr(
    const float* __restrict__ seq, const float* __restrict__ wnorm,
    const float* __restrict__ Wstep, const float* __restrict__ bstep,
    unsigned short* __restrict__ xb, float* __restrict__ lrb)
{
    const int wid = threadIdx.x >> 6, lane = threadIdx.x & 63;
    const int t = blockIdx.x * 4 + wid;
    const float* row = seq + (size_t)t * 512 + lane * 8;
    float v[8];
    *(f32x4*)&v[0] = *(const f32x4*)row;
    *(f32x4*)&v[4] = *(const f32x4*)(row + 4);
    float ss = 0.f;
    #pragma unroll
    for (int j = 0; j < 8; ++j) ss += v[j] * v[j];
    #pragma unroll
    for (int o = 1; o < 64; o <<= 1) ss += __shfl_xor(ss, o);
    float rr = rsqrtf(ss * (1.0f / 512.0f) + 1e-6f);
    const float* wn = wnorm + lane * 8;
    ushort8v xs;
    float acc[8] = {0.f,0.f,0.f,0.f,0.f,0.f,0.f,0.f};
    #pragma unroll
    for (int j = 0; j < 8; ++j) {
        float xf = v[j] * rr * wn[j];
        xs[j] = f2b(xf);
        const float* wrow = Wstep + (size_t)(lane * 8 + j) * 8;
        #pragma unroll
        for (int h = 0; h < 8; ++h) acc[h] = fmaf(xf, wrow[h], acc[h]);
    }
    *(ushort8v*)(xb + (size_t)t * 512 + lane * 8) = xs;
    #pragma unroll
    for (int h = 0; h < 8; ++h) {
        #pragma unroll
        for (int o = 1; o < 64; o <<= 1) acc[h] += __shfl_xor(acc[h], o);
    }
    if (lane == 0) {
        #pragma unroll
        for (int h = 0; h < 8; ++h) lrb[(size_t)t * 8 + h] = sigmoidf(acc[h] + bstep[h]);
    }
}

// ---------------- chunk pooling + mom/dec gates (fused) ---------------------
__global__ __launch_bounds__(256) void k_poolgates(
    const unsigned short* __restrict__ xb,
    const float* __restrict__ Wmom, const float* __restrict__ bmom,
    const float* __restrict__ Wdec, const float* __restrict__ bdec,
    float* __restrict__ momout, float* __restrict__ decout)
{
    __shared__ float sP[4][512];
    __shared__ float pooled[512];
    const int bc = blockIdx.x, tid = threadIdx.x;
    const int q = tid >> 6, lane = tid & 63, d0 = lane * 8;
    float p[8] = {0.f,0.f,0.f,0.f,0.f,0.f,0.f,0.f};
    for (int tt = 0; tt < 16; ++tt) {
        int t = q * 16 + tt;
        ushort8v v = *(const ushort8v*)(xb + (size_t)(bc * 64 + t) * 512 + d0);
        #pragma unroll
        for (int j = 0; j < 8; ++j) p[j] += b2f(v[j]);
    }
    #pragma unroll
    for (int j = 0; j < 8; ++j) sP[q][d0 + j] = p[j];
    __syncthreads();
    #pragma unroll
    for (int half = 0; half < 2; ++half) {
        int d = tid + half * 256;
        pooled[d] = (sP[0][d] + sP[1][d] + sP[2][d] + sP[3][d]) * (1.0f / 64.0f);
    }
    __syncthreads();
    if (tid < 64) {
        const int h = tid & 7, dd0 = tid >> 3;
        float pm = 0.f, pd = 0.f;
        #pragma unroll 8
        for (int it = 0; it < 64; ++it) {
            int d = dd0 + it * 8; float pv = pooled[d];
            pm = fmaf(pv, Wmom[d * 8 + h], pm);
            pd = fmaf(pv, Wdec[d * 8 + h], pd);
        }
        #pragma unroll
        for (int o = 8; o < 64; o <<= 1) { pm += __shfl_xor(pm, o); pd += __shfl_xor(pd, o); }
        if (tid < 8) {
            momout[(size_t)bc * 8 + h] = sigmoidf(pm + bmom[h]);
            decout[(size_t)bc * 8 + h] = sigmoidf(pd + bdec[h]);
        }
    }
}

// ---------------- k/v projection (MFMA, 128x128 tile) ---------------------
__global__ __launch_bounds__(256) void k_proj(
    const unsigned short* __restrict__ xb, const unsigned short* __restrict__ WkvT,
    unsigned short* __restrict__ kbh, unsigned short* __restrict__ vb)
{
    __shared__ __attribute__((aligned(16))) unsigned short As[128][72];
    __shared__ __attribute__((aligned(16))) unsigned short Bs[128][72];
    const int tid = threadIdx.x;
    const int bm = blockIdx.x >> 3, bn = blockIdx.x & 7;
    const int m0 = bm * 128, n0 = bn * 128;
    const int wid = tid >> 6, lane = tid & 63, lg = lane >> 4, lo = lane & 15;
    const int wm = wid >> 1, wn = wid & 1;
    f32x4 acc[4][4];
    #pragma unroll
    for (int i = 0; i < 4; ++i)
        #pragma unroll
        for (int j = 0; j < 4; ++j) acc[i][j] = (f32x4)0.f;

    for (int k0 = 0; k0 < 512; k0 += 64) {
        #pragma unroll
        for (int ii = 0; ii < 4; ++ii) {
            int e0 = tid * 32 + ii * 8;
            int r = e0 >> 6, c = e0 & 63;
            *(bf16x8*)&As[r][c] = *(const bf16x8*)(xb   + (size_t)(m0 + r) * 512 + k0 + c);
            *(bf16x8*)&Bs[r][c] = *(const bf16x8*)(WkvT + (size_t)(n0 + r) * 512 + k0 + c);
        }
        __syncthreads();
        #pragma unroll
        for (int ks = 0; ks < 2; ++ks) {
            bf16x8 aF[4], bF[4];
            #pragma unroll
            for (int mt = 0; mt < 4; ++mt) aF[mt] = *(const bf16x8*)&As[wm * 64 + mt * 16 + lo][ks * 32 + 8 * lg];
            #pragma unroll
            for (int nt = 0; nt < 4; ++nt) bF[nt] = *(const bf16x8*)&Bs[wn * 64 + nt * 16 + lo][ks * 32 + 8 * lg];
            #pragma unroll
            for (int mt = 0; mt < 4; ++mt)
                #pragma unroll
                for (int nt = 0; nt < 4; ++nt) MFMA16(acc[mt][nt], aF[mt], bF[nt]);
        }
        __syncthreads();
    }
    #pragma unroll
    for (int mt = 0; mt < 4; ++mt)
        #pragma unroll
        for (int nt = 0; nt < 4; ++nt)
            #pragma unroll
            for (int r = 0; r < 4; ++r) {
                int row = m0 + wm * 64 + mt * 16 + lg * 4 + r;
                int col = n0 + wn * 64 + nt * 16 + lo;
                unsigned short val = f2b(acc[mt][nt][r]);
                if (col < 512) kbh[(size_t)row * 512 + col] = val;
                else           vb[(size_t)row * 512 + col - 512] = val;
            }
}

// ---------------- coeff scan (LDS-preloaded gates) --------------------------
__global__ void k_coeff(const float* __restrict__ mom, const float* __restrict__ dec,
                        float* __restrict__ coeff, float* __restrict__ Aout)
{
    __shared__ float sm[1024], sd[1024];
    int tid = threadIdx.x;   // 64 threads
    #pragma unroll
    for (int i = 0; i < 4; ++i) {
        int idx = (tid + i * 64) * 4;
        *(f32x4*)&sm[idx] = *(const f32x4*)&mom[idx];
        *(f32x4*)&sd[idx] = *(const f32x4*)&dec[idx];
    }
    __syncthreads();
    int s = tid;
    if (s >= 16) return;
    int b = s >> 3, h = s & 7;
    float P = 1.f, S = 1.f;
    coeff[s * 64 + 63] = 1.f;
    for (int cc = 62; cc >= 0; --cc) {
        float Dn = 1.f - sd[(b * 64 + cc + 1) * 8 + h];
        float Mn = sm[(b * 64 + cc + 1) * 8 + h];
        P *= Dn;
        S = P + Mn * S;
        coeff[s * 64 + cc] = S;
    }
    float D0 = 1.f - sd[(b * 64) * 8 + h];
    Aout[s] = P * D0;
}

// ---------------- forward pass: u, e, eT  (per stream-chunk) ----------------
// double-buffered sG: one barrier per islab  (R8-proven structure)
__global__ __launch_bounds__(256) void k_fwd(
    const unsigned short* __restrict__ kbh, const unsigned short* __restrict__ vb,
    const float* __restrict__ lrb, const float* __restrict__ cfb,
    const unsigned short* __restrict__ w0fT, const unsigned short* __restrict__ w1T,
    unsigned short* __restrict__ uws, unsigned short* __restrict__ ews,
    unsigned short* __restrict__ ewsT)
{
    __shared__ __attribute__((aligned(16))) unsigned short sU[64][72];
    __shared__ __attribute__((aligned(16))) unsigned short sG[2][64][72];
    const int tid = threadIdx.x, blk = blockIdx.x;
    const int s = blk >> 6, c = blk & 63;
    const int b = s >> 3, h = s & 7;
    const int row0 = b * 4096 + c * 64;
    const int wid = tid >> 6, lane = tid & 63, lg = lane >> 4, lo = lane & 15;
    const size_t ubase = (size_t)blk * 4096;

    // P0: per-token rmsnorm of k — thread handles row r = tid>>2, 16 cols
    {
        int r = tid >> 2, c0 = (tid & 3) * 16;
        const unsigned short* kr = kbh + (size_t)(row0 + r) * 512 + h * 64 + c0;
        ushort8v k0 = *(const ushort8v*)kr;
        ushort8v k1 = *(const ushort8v*)(kr + 8);
        float kv[16];
        float ss = 0.f;
        #pragma unroll
        for (int j = 0; j < 8; ++j) { kv[j] = b2f(k0[j]); kv[8 + j] = b2f(k1[j]); }
        #pragma unroll
        for (int j = 0; j < 16; ++j) ss += kv[j] * kv[j];
        ss += __shfl_xor(ss, 1);
        ss += __shfl_xor(ss, 2);
        float rr = rsqrtf(ss * (1.0f / 64.0f) + 1e-6f);
        ushort8v u0, u1;
        #pragma unroll
        for (int j = 0; j < 8; ++j) { u0[j] = f2b(kv[j] * rr); u1[j] = f2b(kv[8 + j] * rr); }
        *(ushort8v*)&sU[r][c0]     = u0;
        *(ushort8v*)&sU[r][c0 + 8] = u1;
        *(ushort8v*)(uws + ubase + r * 64 + c0)     = u0;
        *(ushort8v*)(uws + ubase + r * 64 + c0 + 8) = u1;
    }
    __syncthreads();

    const unsigned short* w0h = w0fT + h * 16384;
    const unsigned short* w1h = w1T  + h * 16384;
    bf16x8 aF0 = *(const bf16x8*)&sU[wid * 16 + lo][8 * lg];
    bf16x8 aF1 = *(const bf16x8*)&sU[wid * 16 + lo][32 + 8 * lg];

    f32x4 yac[4];
    #pragma unroll
    for (int nt = 0; nt < 4; ++nt) yac[nt] = (f32x4)0.f;

    for (int is = 0; is < 4; ++is) {
        const int bi = is & 1;
        f32x4 a1[4];
        #pragma unroll
        for (int nt = 0; nt < 4; ++nt) a1[nt] = (f32x4)0.f;
        #pragma unroll
        for (int nt = 0; nt < 4; ++nt) {
            bf16x8 b0 = *(const bf16x8*)(w0h + (size_t)(is * 64 + nt * 16 + lo) * 64 + 8 * lg);
            bf16x8 b1 = *(const bf16x8*)(w0h + (size_t)(is * 64 + nt * 16 + lo) * 64 + 32 + 8 * lg);
            MFMA16(a1[nt], aF0, b0);
            MFMA16(a1[nt], aF1, b1);
        }
        #pragma unroll
        for (int nt = 0; nt < 4; ++nt)
            #pragma unroll
            for (int r = 0; r < 4; ++r) {
                int t = wid * 16 + lg * 4 + r;
                sG[bi][t][nt * 16 + lo] = f2b(gelu_g(a1[nt][r]));
            }
        __syncthreads();
        #pragma unroll
        for (int ks = 0; ks < 2; ++ks) {
            bf16x8 aW = *(const bf16x8*)(w1h + (size_t)(wid * 16 + lo) * 256 + is * 64 + ks * 32 + 8 * lg);
            #pragma unroll
            for (int nt = 0; nt < 4; ++nt) {
                bf16x8 bG = *(const bf16x8*)&sG[bi][nt * 16 + lo][ks * 32 + 8 * lg];
                MFMA16(yac[nt], aW, bG);
            }
        }
    }

    // P2: scaled error e -> ews (row-major, bf16)
    float coefv = cfb[s * 64 + c];
    ushort4v evs[4];
    #pragma unroll
    for (int nt = 0; nt < 4; ++nt) {
        int t = nt * 16 + lo; int grow = row0 + t;
        float sc = -coefv * lrb[(size_t)grow * 8 + h] * (2.0f / 64.0f);
        ushort4v k4 = *(const ushort4v*)(kbh + (size_t)grow * 512 + h * 64 + wid * 16 + lg * 4);
        ushort4v v4 = *(const ushort4v*)(vb  + (size_t)grow * 512 + h * 64 + wid * 16 + lg * 4);
        ushort4v ev;
        #pragma unroll
        for (int r = 0; r < 4; ++r)
            ev[r] = f2b(sc * (yac[nt][r] + b2f(k4[r]) - b2f(v4[r])));
        evs[nt] = ev;
        *(ushort4v*)(ews + ubase + t * 64 + wid * 16 + lg * 4) = ev;
    }

    // P3: transpose e -> ewsT via sG[0] (last GEMM2 read sG[1]; safe)
    #pragma unroll
    for (int nt = 0; nt < 4; ++nt)
        *(ushort4v*)&sG[0][nt * 16 + lo][wid * 16 + lg * 4] = evs[nt];
    __syncthreads();
    {
        int r2 = tid >> 2, c2 = (tid & 3) * 16;
        ushort8v o0, o1;
        #pragma unroll
        for (int jj = 0; jj < 8; ++jj) o0[jj] = sG[0][c2 + jj][r2];
        #pragma unroll
        for (int jj = 0; jj < 8; ++jj) o1[jj] = sG[0][c2 + 8 + jj][r2];
        *(ushort8v*)(ewsT + ubase + r2 * 64 + c2)     = o0;
        *(ushort8v*)(ewsT + ubase + r2 * 64 + c2 + 8) = o1;
    }
}

// ---------------- backward: per (s, kslice/8, islab) -----------------------
// dbuf LDS, software-pipelined global loads (2 static register sets), fp32 partials
#define LOADSET(BASE, UTG, U4N, AF0, AF1, EF0, EF1)                                      \
    {                                                                                     \
        _Pragma("unroll")                                                                 \
        for (int ks = 0; ks < 2; ++ks)                                                    \
            _Pragma("unroll")                                                             \
            for (int jj = 0; jj < 8; ++jj)                                                \
                UTG[ks * 8 + jj] = uws[(BASE) + (size_t)(ks * 32 + 8 * lg + jj) * 64 + wid * 16 + lo]; \
        _Pragma("unroll")                                                                 \
        for (int nt = 0; nt < 4; ++nt)                                                    \
            U4N[nt] = *(const ushort4v*)(uws + (BASE) + (size_t)(nt * 16 + lo) * 64 + wid * 16 + lg * 4); \
        AF0 = *(const bf16x8*)(uws + (BASE) + (size_t)(wid * 16 + lo) * 64 + 8 * lg);     \
        AF1 = *(const bf16x8*)(uws + (BASE) + (size_t)(wid * 16 + lo) * 64 + 32 + 8 * lg);\
        EF0 = *(const bf16x8*)(ews + (BASE) + (size_t)(wid * 16 + lo) * 64 + 8 * lg);     \
        EF1 = *(const bf16x8*)(ews + (BASE) + (size_t)(wid * 16 + lo) * 64 + 32 + 8 * lg);\
    }

#define PHASEA(BI, AF0, AF1, EF0, EF1)                                                    \
    {                                                                                     \
        f32x4 a1[4];                                                                      \
        _Pragma("unroll") for (int nt = 0; nt < 4; ++nt) a1[nt] = (f32x4)0.f;             \
        _Pragma("unroll") for (int nt = 0; nt < 4; ++nt) {                                \
            bf16x8 b0 = *(const bf16x8*)(w0fh + (size_t)(is * 64 + nt * 16 + lo) * 64 + 8 * lg);      \
            bf16x8 b1 = *(const bf16x8*)(w0fh + (size_t)(is * 64 + nt * 16 + lo) * 64 + 32 + 8 * lg); \
            MFMA16(a1[nt], AF0, b0);                                                      \
            MFMA16(a1[nt], AF1, b1);                                                      \
        }                                                                                 \
        float gpv[4][4];                                                                  \
        _Pragma("unroll") for (int nt = 0; nt < 4; ++nt) {                                \
            ushort4v gv;                                                                  \
            _Pragma("unroll") for (int r = 0; r < 4; ++r) {                               \
                float g, gp; gelu_both(a1[nt][r], g, gp);                                 \
                gv[r] = f2b(g); gpv[nt][r] = gp;                                          \
            }                                                                             \
            *(ushort4v*)&sGT[BI][nt * 16 + lo][wid * 16 + lg * 4] = gv;                   \
        }                                                                                 \
        f32x4 dga[4];                                                                     \
        _Pragma("unroll") for (int nt = 0; nt < 4; ++nt) dga[nt] = (f32x4)0.f;            \
        _Pragma("unroll") for (int nt = 0; nt < 4; ++nt) {                                \
            bf16x8 b0 = *(const bf16x8*)(w1nh + (size_t)(is * 64 + nt * 16 + lo) * 64 + 8 * lg);      \
            bf16x8 b1 = *(const bf16x8*)(w1nh + (size_t)(is * 64 + nt * 16 + lo) * 64 + 32 + 8 * lg); \
            MFMA16(dga[nt], EF0, b0);                                                     \
            MFMA16(dga[nt], EF1, b1);                                                     \
        }                                                                                 \
        _Pragma("unroll") for (int nt = 0; nt < 4; ++nt) {                                \
            ushort4v dv;                                                                  \
            _Pragma("unroll") for (int r = 0; r < 4; ++r) dv[r] = f2b(dga[nt][r] * gpv[nt][r]);       \
            *(ushort4v*)&sDAT[BI][nt * 16 + lo][wid * 16 + lg * 4] = dv;                  \
            _Pragma("unroll") for (int r = 0; r < 4; ++r)                                 \
                sDAN[BI][wid * 16 + lg * 4 + r][nt * 16 + lo] = dv[r];                    \
        }                                                                                 \
    }

#define PHASEB(BI, BASE, UTG, U4N)                                                        \
    {                                                                                     \
        _Pragma("unroll") for (int ks = 0; ks < 2; ++ks) {                                \
            bf16x8 aG = *(const bf16x8*)&sGT[BI][wid * 16 + lo][ks * 32 + 8 * lg];        \
            _Pragma("unroll") for (int nt = 0; nt < 4; ++nt) {                            \
                bf16x8 bE = *(const bf16x8*)(ewsT + (BASE) + (size_t)(nt * 16 + lo) * 64 + ks * 32 + 8 * lg); \
                MFMA16(gw1a[nt], aG, bE);                                                 \
            }                                                                             \
        }                                                                                 \
        _Pragma("unroll") for (int ks = 0; ks < 2; ++ks) {                                \
            union { ushort8v u; bf16x8 b; } cu;                                           \
            _Pragma("unroll") for (int jj = 0; jj < 8; ++jj) cu.u[jj] = UTG[ks * 8 + jj]; \
            _Pragma("unroll") for (int nt = 0; nt < 4; ++nt) {                            \
                bf16x8 bD = *(const bf16x8*)&sDAT[BI][nt * 16 + lo][ks * 32 + 8 * lg];    \
                MFMA16(gw0a[nt], cu.b, bD);                                               \
            }                                                                             \
        }                                                                                 \
        f32x4 dht[4];                                                                     \
        _Pragma("unroll") for (int nt = 0; nt < 4; ++nt) dht[nt] = (f32x4)0.f;            \
        _Pragma("unroll") for (int ks = 0; ks < 2; ++ks) {                                \
            bf16x8 aW0 = *(const bf16x8*)(w0nh + (size_t)(wid * 16 + lo) * 256 + is * 64 + ks * 32 + 8 * lg); \
            _Pragma("unroll") for (int nt = 0; nt < 4; ++nt) {                            \
                bf16x8 bDA = *(const bf16x8*)&sDAN[BI][nt * 16 + lo][ks * 32 + 8 * lg];   \
                MFMA16(dht[nt], aW0, bDA);                                                \
            }                                                                             \
        }                                                                                 \
        _Pragma("unroll") for (int nt = 0; nt < 4; ++nt)                                  \
            _Pragma("unroll") for (int r = 0; r < 4; ++r)                                 \
                gnwp[r] += b2f(U4N[nt][r]) * dht[nt][r];                                  \
    }

__global__ __launch_bounds__(256) void k_bwd(
    const unsigned short* __restrict__ uws, const unsigned short* __restrict__ ews,
    const unsigned short* __restrict__ ewsT,
    const unsigned short* __restrict__ w0fT, const unsigned short* __restrict__ w0N,
    const unsigned short* __restrict__ w1N, const float* __restrict__ nw_g,
    float* __restrict__ pws, float* __restrict__ gnwb)
{
    __shared__ __attribute__((aligned(16))) unsigned short sGT[2][64][72];
    __shared__ __attribute__((aligned(16))) unsigned short sDAT[2][64][72];
    __shared__ __attribute__((aligned(16))) unsigned short sDAN[2][64][68];
    const int tid = threadIdx.x, blk = blockIdx.x;
    const int s = blk >> 5, ksl = (blk >> 2) & 7, is = blk & 3;
    const int h = s & 7;
    const int wid = tid >> 6, lane = tid & 63, lg = lane >> 4, lo = lane & 15;

    f32x4 gw1a[4], gw0a[4];
    #pragma unroll
    for (int nt = 0; nt < 4; ++nt) { gw1a[nt] = (f32x4)0.f; gw0a[nt] = (f32x4)0.f; }
    float gnwp[4] = {0.f, 0.f, 0.f, 0.f};

    const unsigned short* w0fh = w0fT + h * 16384;
    const unsigned short* w0nh = w0N  + h * 16384;
    const unsigned short* w1nh = w1N  + h * 16384;

    // software-pipelined loop: 8 chunks, unrolled x2 with static A/B reg sets
    unsigned short utgA[16], utgB[16];
    ushort4v u4nA[4], u4nB[4];
    bf16x8 aF0A, aF1A, eF0A, eF1A, aF0B, aF1B, eF0B, eF1B;
    const size_t sbase = (size_t)(s * 64 + ksl * 8) * 4096;
    LOADSET(sbase, utgA, u4nA, aF0A, aF1A, eF0A, eF1A);

    for (int t2 = 0; t2 < 4; ++t2) {
        const size_t base0 = sbase + (size_t)(t2 * 2) * 4096;
        const size_t base1 = base0 + 4096;
        const size_t base2 = (t2 < 3) ? (base1 + 4096) : base1;  // clamp: last prefetch is dummy

        // ---- even iter (bi=0, consumes set A) ----
        PHASEA(0, aF0A, aF1A, eF0A, eF1A);
        __syncthreads();
        LOADSET(base1, utgB, u4nB, aF0B, aF1B, eF0B, eF1B);      // prefetch under phase B
        PHASEB(0, base0, utgA, u4nA);

        // ---- odd iter (bi=1, consumes set B) ----
        PHASEA(1, aF0B, aF1B, eF0B, eF1B);
        __syncthreads();
        LOADSET(base2, utgA, u4nA, aF0A, aF1A, eF0A, eF1A);      // prefetch under phase B
        PHASEB(1, base1, utgB, u4nB);
    }

    // epilogue: fp32 partials (record = 8192: gw1 4096 + gw0 4096); gnw fp32
    size_t pb = (size_t)blk * 8192;
    #pragma unroll
    for (int nt = 0; nt < 4; ++nt)
        #pragma unroll
        for (int r = 0; r < 4; ++r)
            pws[pb + (size_t)(wid * 16 + lg * 4 + r) * 64 + nt * 16 + lo] = gw1a[nt][r];
    #pragma unroll
    for (int r = 0; r < 4; ++r) {
        float nwv = nw_g[h * 64 + wid * 16 + lg * 4 + r];
        #pragma unroll
        for (int nt = 0; nt < 4; ++nt)
            pws[pb + 4096 + (size_t)(wid * 16 + lg * 4 + r) * 64 + nt * 16 + lo] = nwv * gw0a[nt][r];
    }
    #pragma unroll
    for (int r = 0; r < 4; ++r) {
        #pragma unroll
        for (int o = 1; o < 16; o <<= 1) gnwp[r] += __shfl_xor(gnwp[r], o);
    }
    if (lo == 0) {
        #pragma unroll
        for (int r = 0; r < 4; ++r)
            gnwb[(size_t)blk * 64 + wid * 16 + lg * 4 + r] = gnwp[r];
    }
}

// ---------------- final reduce: out = A*param0 + sum of partials -----------
__global__ __launch_bounds__(256) void k_reduce(
    const float* __restrict__ pws, const float* __restrict__ gnwb,
    const float* __restrict__ Ab,
    const float* __restrict__ nw_g, const float* __restrict__ w0_g,
    const float* __restrict__ w1_g, float* __restrict__ out)
{
    int gid = blockIdx.x * 256 + threadIdx.x;
    if (gid >= 16 * 32832) return;
    int s = gid / 32832, r = gid % 32832;
    int h = s & 7;
    float A = Ab[s];
    float val;
    if (r < 64) {
        val = A * nw_g[h * 64 + r];
        #pragma unroll
        for (int ks = 0; ks < 8; ++ks)
            #pragma unroll
            for (int i2 = 0; i2 < 4; ++i2)
                val += gnwb[(size_t)(s * 32 + ks * 4 + i2) * 64 + r];
    } else if (r < 16448) {
        int rr = r - 64; int d = rr >> 8; int i = rr & 255; int i2 = i >> 6, iloc = i & 63;
        val = A * w0_g[h * 16384 + rr];
        #pragma unroll
        for (int ks = 0; ks < 8; ++ks)
            val += pws[(size_t)(s * 32 + ks * 4 + i2) * 8192 + 4096 + d * 64 + iloc];
    } else {
        int rr = r - 16448; int i = rr >> 6; int j = rr & 63; int i2 = i >> 6, iloc = i & 63;
        val = A * w1_g[h * 16384 + rr];
        #pragma unroll
        for (int ks = 0; ks < 8; ++ks)
            val += pws[(size_t)(s * 32 + ks * 4 + i2) * 8192 + iloc * 64 + j];
    }
    out[gid] = val;
}

// ---------------- launcher -------------------------------------------------
extern "C" void kernel_launch(void* const* d_in, const int* in_sizes, int n_in,
                              void* d_out, int out_size, void* d_ws, size_t ws_size,
                              hipStream_t stream) {
    (void)in_sizes; (void)n_in; (void)out_size; (void)ws_size;
    const float* seq   = (const float*)d_in[0];
    const float* snw   = (const float*)d_in[1];
    const float* Wk    = (const float*)d_in[2];
    const float* Wv    = (const float*)d_in[3];
    const float* Wstep = (const float*)d_in[4];
    const float* bstep = (const float*)d_in[5];
    const float* Wmom  = (const float*)d_in[6];
    const float* bmom  = (const float*)d_in[7];
    const float* Wdec  = (const float*)d_in[8];
    const float* bdec  = (const float*)d_in[9];
    const float* nw_g  = (const float*)d_in[10];
    const float* w0_g  = (const float*)d_in[11];
    const float* w1_g  = (const float*)d_in[12];
    float* out = (float*)d_out;

    // workspace layout (max offset 44,318,720 B — identical to R12)
    char* ws = (char*)d_ws;
    unsigned short* xb   = (unsigned short*)(ws + 0);          //  8,388,608  dead after k_proj
    unsigned short* uws  = (unsigned short*)(ws + 0);          //  8,388,608  alias xb; k_fwd -> k_bwd
    unsigned short* WkvT = (unsigned short*)(ws + 8388608);    //  1,048,576  dead after k_proj
    float*          gnwb = (float*)        (ws + 8388608);     //    131,072  alias WkvT; k_bwd -> k_reduce
    unsigned short* kbh  = (unsigned short*)(ws + 9437184);    //  8,388,608  dead after k_fwd
    unsigned short* vb   = (unsigned short*)(ws + 17825792);   //  8,388,608  dead after k_fwd
    float*          pws  = (float*)        (ws + 9437184);     // 16,777,216  fp32, alias kbh+vb
    unsigned short* ews  = (unsigned short*)(ws + 26214400);   //  8,388,608
    unsigned short* ewsT = (unsigned short*)(ws + 34603008);   //  8,388,608
    unsigned short* w0fT = (unsigned short*)(ws + 42991616);   //    262,144
    unsigned short* w1T  = (unsigned short*)(ws + 43253760);   //    262,144
    unsigned short* w0N  = (unsigned short*)(ws + 43515904);   //    262,144
    unsigned short* w1N  = (unsigned short*)(ws + 43778048);   //    262,144
    float* lrb  = (float*)(ws + 44040192);                     //    262,144
    float* momb = (float*)(ws + 44302336);                     //      4,096
    float* decb = (float*)(ws + 44306432);                     //      4,096
    float* cfb  = (float*)(ws + 44310528);                     //      4,096
    float* Ab   = (float*)(ws + 44314624);                     //         64

    k_wprep    <<<320, 256, 0, stream>>>(Wk, Wv, w0_g, w1_g, nw_g, WkvT, w0fT, w1T, w0N, w1N);
    k_rms_lr   <<<2048, 256, 0, stream>>>(seq, snw, Wstep, bstep, xb, lrb);
    k_poolgates<<<128, 256, 0, stream>>>(xb, Wmom, bmom, Wdec, bdec, momb, decb);
    k_proj     <<<512, 256, 0, stream>>>(xb, WkvT, kbh, vb);
    k_coeff    <<<1, 64, 0, stream>>>(momb, decb, cfb, Ab);
    k_fwd      <<<1024, 256, 0, stream>>>(kbh, vb, lrb, cfb, w0fT, w1T, uws, ews, ewsT);
    k_bwd      <<<512, 256, 0, stream>>>(uws, ews, ewsT, w0fT, w0N, w1N, nw_g, pws, gnwb);
    k_reduce   <<<2052, 256, 0, stream>>>(pws, gnwb, Ab, nw_g, w0_g, w1_g, out);
}

// Round 14
// 132.671 us; speedup vs baseline: 1.1165x; 1.1165x over previous
//
#include <hip/hip_runtime.h>
#include <math.h>

// ---------------- types ----------------
typedef __attribute__((ext_vector_type(8)))  __bf16 bf16x8;
typedef __attribute__((ext_vector_type(4)))  float  f32x4;
typedef __attribute__((ext_vector_type(4)))  unsigned short ushort4v;
typedef __attribute__((ext_vector_type(8)))  unsigned short ushort8v;

#define MFMA16(acc, a, b) acc = __builtin_amdgcn_mfma_f32_16x16x32_bf16((a),(b),(acc),0,0,0)

__device__ inline unsigned short f2b(float f) {
    __bf16 b = (__bf16)f;                      // native RNE cvt (single op)
    union { __bf16 b; unsigned short u; } v; v.b = b;
    return v.u;
}
__device__ inline float b2f(unsigned short h) {
    union { unsigned int u; float f; } v; v.u = ((unsigned int)h) << 16;
    return v.f;
}
__device__ inline float fast_rcp(float x) { return __builtin_amdgcn_rcpf(x); }
__device__ inline float tanh_fast(float z) {
    float e = __expf(2.0f * z);
    return 1.0f - 2.0f * fast_rcp(e + 1.0f);   // rcp instead of precise div
}
__device__ inline float gelu_g(float x) {
    const float c0 = 0.7978845608028654f, c1 = 0.044715f;
    float z = c0 * x * (1.0f + c1 * x * x);
    return 0.5f * x * (1.0f + tanh_fast(z));
}
__device__ inline void gelu_both(float x, float& g, float& gp) {
    const float c0 = 0.7978845608028654f, c1 = 0.044715f;
    float x2 = x * x;
    float z  = c0 * x * (1.0f + c1 * x2);
    float t  = tanh_fast(z);
    g  = 0.5f * x * (1.0f + t);
    float dz = c0 * (1.0f + 3.0f * c1 * x2);
    gp = 0.5f * (1.0f + t) + 0.5f * x * (1.0f - t * t) * dz;
}
__device__ inline float sigmoidf(float x) { return fast_rcp(1.0f + __expf(-x)); }

// ---------------- weight prep: bf16 converts + transposes ----------------
__global__ __launch_bounds__(256) void k_wprep(
    const float* __restrict__ Wk, const float* __restrict__ Wv,
    const float* __restrict__ w0_g, const float* __restrict__ w1_g,
    const float* __restrict__ nw_g,
    unsigned short* __restrict__ WkvT, unsigned short* __restrict__ w0fT,
    unsigned short* __restrict__ w1T, unsigned short* __restrict__ w0N,
    unsigned short* __restrict__ w1N)
{
    const int bid = blockIdx.x, tid = threadIdx.x;
    __shared__ float tile[64][65];
    if (bid < 128) {
        int kt = bid >> 4, nt = bid & 15;
        const float* src = (nt < 8) ? Wk : Wv;
        int ncol0 = (nt & 7) * 64;
        for (int ii = 0; ii < 16; ++ii) {
            int idx = tid + ii * 256; int r = idx >> 6, cc = idx & 63;
            tile[r][cc] = src[(size_t)(kt * 64 + r) * 512 + ncol0 + cc];
        }
        __syncthreads();
        for (int ii = 0; ii < 16; ++ii) {
            int idx = tid + ii * 256; int r = idx >> 6, cc = idx & 63;
            WkvT[(size_t)(nt * 64 + r) * 512 + kt * 64 + cc] = f2b(tile[cc][r]);
        }
    } else if (bid < 160) {
        int q = bid - 128; int hh = q >> 2, it = q & 3;
        const float* w0h = w0_g + hh * 16384;
        for (int ii = 0; ii < 16; ++ii) {
            int idx = tid + ii * 256; int r = idx >> 6, cc = idx & 63;
            tile[r][cc] = w0h[r * 256 + it * 64 + cc];
        }
        __syncthreads();
        for (int ii = 0; ii < 16; ++ii) {
            int idx = tid + ii * 256; int r = idx >> 6, cc = idx & 63;
            w0fT[hh * 16384 + (it * 64 + r) * 64 + cc] = f2b(nw_g[hh * 64 + cc] * tile[cc][r]);
        }
    } else if (bid < 192) {
        int q = bid - 160; int hh = q >> 2, it = q & 3;
        const float* w1h = w1_g + hh * 16384;
        for (int ii = 0; ii < 16; ++ii) {
            int idx = tid + ii * 256; int r = idx >> 6, cc = idx & 63;
            tile[r][cc] = w1h[(it * 64 + r) * 64 + cc];
        }
        __syncthreads();
        for (int ii = 0; ii < 16; ++ii) {
            int idx = tid + ii * 256; int r = idx >> 6, cc = idx & 63;
            w1T[hh * 16384 + r * 256 + it * 64 + cc] = f2b(tile[cc][r]);
        }
    } else {
        int q = bid - 192;
        int gid = q * 2048 + tid * 8;
        const float* s; unsigned short* d;
        if (gid < 131072) { s = w0_g + gid; d = w0N + gid; }
        else              { s = w1_g + (gid - 131072); d = w1N + (gid - 131072); }
        #pragma unroll
        for (int jj = 0; jj < 8; ++jj) d[jj] = f2b(s[jj]);
    }
}

// ---------------- rmsnorm(seq)->xb(bf16)  +  lr projection (fused) --------
__global__ __launch_bounds__(256) void k_rms_lr(
    const float* __restrict__ seq, const float* __restrict__ wnorm,
    const float* __restrict__ Wstep, const float* __restrict__ bstep,
    unsigned short* __restrict__ xb, float* __restrict__ lrb)
{
    const int wid = threadIdx.x >> 6, lane = threadIdx.x & 63;
    const int t = blockIdx.x * 4 + wid;
    const float* row = seq + (size_t)t * 512 + lane * 8;
    float v[8];
    *(f32x4*)&v[0] = *(const f32x4*)row;
    *(f32x4*)&v[4] = *(const f32x4*)(row + 4);
    float ss = 0.f;
    #pragma unroll
    for (int j = 0; j < 8; ++j) ss += v[j] * v[j];
    #pragma unroll
    for (int o = 1; o < 64; o <<= 1) ss += __shfl_xor(ss, o);
    float rr = rsqrtf(ss * (1.0f / 512.0f) + 1e-6f);
    const float* wn = wnorm + lane * 8;
    ushort8v xs;
    float acc[8] = {0.f,0.f,0.f,0.f,0.f,0.f,0.f,0.f};
    #pragma unroll
    for (int j = 0; j < 8; ++j) {
        float xf = v[j] * rr * wn[j];
        xs[j] = f2b(xf);
        const float* wrow = Wstep + (size_t)(lane * 8 + j) * 8;
        #pragma unroll
        for (int h = 0; h < 8; ++h) acc[h] = fmaf(xf, wrow[h], acc[h]);
    }
    *(ushort8v*)(xb + (size_t)t * 512 + lane * 8) = xs;
    #pragma unroll
    for (int h = 0; h < 8; ++h) {
        #pragma unroll
        for (int o = 1; o < 64; o <<= 1) acc[h] += __shfl_xor(acc[h], o);
    }
    if (lane == 0) {
        #pragma unroll
        for (int h = 0; h < 8; ++h) lrb[(size_t)t * 8 + h] = sigmoidf(acc[h] + bstep[h]);
    }
}

// ---------------- chunk pooling + mom/dec gates (fused) ---------------------
__global__ __launch_bounds__(256) void k_poolgates(
    const unsigned short* __restrict__ xb,
    const float* __restrict__ Wmom, const float* __restrict__ bmom,
    const float* __restrict__ Wdec, const float* __restrict__ bdec,
    float* __restrict__ momout, float* __restrict__ decout)
{
    __shared__ float sP[4][512];
    __shared__ float pooled[512];
    const int bc = blockIdx.x, tid = threadIdx.x;
    const int q = tid >> 6, lane = tid & 63, d0 = lane * 8;
    float p[8] = {0.f,0.f,0.f,0.f,0.f,0.f,0.f,0.f};
    for (int tt = 0; tt < 16; ++tt) {
        int t = q * 16 + tt;
        ushort8v v = *(const ushort8v*)(xb + (size_t)(bc * 64 + t) * 512 + d0);
        #pragma unroll
        for (int j = 0; j < 8; ++j) p[j] += b2f(v[j]);
    }
    #pragma unroll
    for (int j = 0; j < 8; ++j) sP[q][d0 + j] = p[j];
    __syncthreads();
    #pragma unroll
    for (int half = 0; half < 2; ++half) {
        int d = tid + half * 256;
        pooled[d] = (sP[0][d] + sP[1][d] + sP[2][d] + sP[3][d]) * (1.0f / 64.0f);
    }
    __syncthreads();
    if (tid < 64) {
        const int h = tid & 7, dd0 = tid >> 3;
        float pm = 0.f, pd = 0.f;
        #pragma unroll 8
        for (int it = 0; it < 64; ++it) {
            int d = dd0 + it * 8; float pv = pooled[d];
            pm = fmaf(pv, Wmom[d * 8 + h], pm);
            pd = fmaf(pv, Wdec[d * 8 + h], pd);
        }
        #pragma unroll
        for (int o = 8; o < 64; o <<= 1) { pm += __shfl_xor(pm, o); pd += __shfl_xor(pd, o); }
        if (tid < 8) {
            momout[(size_t)bc * 8 + h] = sigmoidf(pm + bmom[h]);
            decout[(size_t)bc * 8 + h] = sigmoidf(pd + bdec[h]);
        }
    }
}

// ---------------- k/v projection (MFMA, 128x128 tile) ---------------------
__global__ __launch_bounds__(256) void k_proj(
    const unsigned short* __restrict__ xb, const unsigned short* __restrict__ WkvT,
    unsigned short* __restrict__ kbh, unsigned short* __restrict__ vb)
{
    __shared__ __attribute__((aligned(16))) unsigned short As[128][72];
    __shared__ __attribute__((aligned(16))) unsigned short Bs[128][72];
    const int tid = threadIdx.x;
    const int bm = blockIdx.x >> 3, bn = blockIdx.x & 7;
    const int m0 = bm * 128, n0 = bn * 128;
    const int wid = tid >> 6, lane = tid & 63, lg = lane >> 4, lo = lane & 15;
    const int wm = wid >> 1, wn = wid & 1;
    f32x4 acc[4][4];
    #pragma unroll
    for (int i = 0; i < 4; ++i)
        #pragma unroll
        for (int j = 0; j < 4; ++j) acc[i][j] = (f32x4)0.f;

    for (int k0 = 0; k0 < 512; k0 += 64) {
        #pragma unroll
        for (int ii = 0; ii < 4; ++ii) {
            int e0 = tid * 32 + ii * 8;
            int r = e0 >> 6, c = e0 & 63;
            *(bf16x8*)&As[r][c] = *(const bf16x8*)(xb   + (size_t)(m0 + r) * 512 + k0 + c);
            *(bf16x8*)&Bs[r][c] = *(const bf16x8*)(WkvT + (size_t)(n0 + r) * 512 + k0 + c);
        }
        __syncthreads();
        #pragma unroll
        for (int ks = 0; ks < 2; ++ks) {
            bf16x8 aF[4], bF[4];
            #pragma unroll
            for (int mt = 0; mt < 4; ++mt) aF[mt] = *(const bf16x8*)&As[wm * 64 + mt * 16 + lo][ks * 32 + 8 * lg];
            #pragma unroll
            for (int nt = 0; nt < 4; ++nt) bF[nt] = *(const bf16x8*)&Bs[wn * 64 + nt * 16 + lo][ks * 32 + 8 * lg];
            #pragma unroll
            for (int mt = 0; mt < 4; ++mt)
                #pragma unroll
                for (int nt = 0; nt < 4; ++nt) MFMA16(acc[mt][nt], aF[mt], bF[nt]);
        }
        __syncthreads();
    }
    #pragma unroll
    for (int mt = 0; mt < 4; ++mt)
        #pragma unroll
        for (int nt = 0; nt < 4; ++nt)
            #pragma unroll
            for (int r = 0; r < 4; ++r) {
                int row = m0 + wm * 64 + mt * 16 + lg * 4 + r;
                int col = n0 + wn * 64 + nt * 16 + lo;
                unsigned short val = f2b(acc[mt][nt][r]);
                if (col < 512) kbh[(size_t)row * 512 + col] = val;
                else           vb[(size_t)row * 512 + col - 512] = val;
            }
}

// ---------------- coeff scan (LDS-preloaded gates) --------------------------
__global__ void k_coeff(const float* __restrict__ mom, const float* __restrict__ dec,
                        float* __restrict__ coeff, float* __restrict__ Aout)
{
    __shared__ float sm[1024], sd[1024];
    int tid = threadIdx.x;   // 64 threads
    #pragma unroll
    for (int i = 0; i < 4; ++i) {
        int idx = (tid + i * 64) * 4;
        *(f32x4*)&sm[idx] = *(const f32x4*)&mom[idx];
        *(f32x4*)&sd[idx] = *(const f32x4*)&dec[idx];
    }
    __syncthreads();
    int s = tid;
    if (s >= 16) return;
    int b = s >> 3, h = s & 7;
    float P = 1.f, S = 1.f;
    coeff[s * 64 + 63] = 1.f;
    for (int cc = 62; cc >= 0; --cc) {
        float Dn = 1.f - sd[(b * 64 + cc + 1) * 8 + h];
        float Mn = sm[(b * 64 + cc + 1) * 8 + h];
        P *= Dn;
        S = P + Mn * S;
        coeff[s * 64 + cc] = S;
    }
    float D0 = 1.f - sd[(b * 64) * 8 + h];
    Aout[s] = P * D0;
}

// ---------------- forward pass: u, e  (per stream-chunk) --------------------
// double-buffered sG: one barrier per islab; NO eT (built in k_bwd's LDS now)
__global__ __launch_bounds__(256) void k_fwd(
    const unsigned short* __restrict__ kbh, const unsigned short* __restrict__ vb,
    const float* __restrict__ lrb, const float* __restrict__ cfb,
    const unsigned short* __restrict__ w0fT, const unsigned short* __restrict__ w1T,
    unsigned short* __restrict__ uws, unsigned short* __restrict__ ews)
{
    __shared__ __attribute__((aligned(16))) unsigned short sU[64][72];
    __shared__ __attribute__((aligned(16))) unsigned short sG[2][64][72];
    const int tid = threadIdx.x, blk = blockIdx.x;
    const int s = blk >> 6, c = blk & 63;
    const int b = s >> 3, h = s & 7;
    const int row0 = b * 4096 + c * 64;
    const int wid = tid >> 6, lane = tid & 63, lg = lane >> 4, lo = lane & 15;
    const size_t ubase = (size_t)blk * 4096;

    // P0: per-token rmsnorm of k — thread handles row r = tid>>2, 16 cols
    {
        int r = tid >> 2, c0 = (tid & 3) * 16;
        const unsigned short* kr = kbh + (size_t)(row0 + r) * 512 + h * 64 + c0;
        ushort8v k0 = *(const ushort8v*)kr;
        ushort8v k1 = *(const ushort8v*)(kr + 8);
        float kv[16];
        float ss = 0.f;
        #pragma unroll
        for (int j = 0; j < 8; ++j) { kv[j] = b2f(k0[j]); kv[8 + j] = b2f(k1[j]); }
        #pragma unroll
        for (int j = 0; j < 16; ++j) ss += kv[j] * kv[j];
        ss += __shfl_xor(ss, 1);
        ss += __shfl_xor(ss, 2);
        float rr = rsqrtf(ss * (1.0f / 64.0f) + 1e-6f);
        ushort8v u0, u1;
        #pragma unroll
        for (int j = 0; j < 8; ++j) { u0[j] = f2b(kv[j] * rr); u1[j] = f2b(kv[8 + j] * rr); }
        *(ushort8v*)&sU[r][c0]     = u0;
        *(ushort8v*)&sU[r][c0 + 8] = u1;
        *(ushort8v*)(uws + ubase + r * 64 + c0)     = u0;
        *(ushort8v*)(uws + ubase + r * 64 + c0 + 8) = u1;
    }
    __syncthreads();

    const unsigned short* w0h = w0fT + h * 16384;
    const unsigned short* w1h = w1T  + h * 16384;
    bf16x8 aF0 = *(const bf16x8*)&sU[wid * 16 + lo][8 * lg];
    bf16x8 aF1 = *(const bf16x8*)&sU[wid * 16 + lo][32 + 8 * lg];

    f32x4 yac[4];
    #pragma unroll
    for (int nt = 0; nt < 4; ++nt) yac[nt] = (f32x4)0.f;

    for (int is = 0; is < 4; ++is) {
        const int bi = is & 1;
        f32x4 a1[4];
        #pragma unroll
        for (int nt = 0; nt < 4; ++nt) a1[nt] = (f32x4)0.f;
        #pragma unroll
        for (int nt = 0; nt < 4; ++nt) {
            bf16x8 b0 = *(const bf16x8*)(w0h + (size_t)(is * 64 + nt * 16 + lo) * 64 + 8 * lg);
            bf16x8 b1 = *(const bf16x8*)(w0h + (size_t)(is * 64 + nt * 16 + lo) * 64 + 32 + 8 * lg);
            MFMA16(a1[nt], aF0, b0);
            MFMA16(a1[nt], aF1, b1);
        }
        #pragma unroll
        for (int nt = 0; nt < 4; ++nt)
            #pragma unroll
            for (int r = 0; r < 4; ++r) {
                int t = wid * 16 + lg * 4 + r;
                sG[bi][t][nt * 16 + lo] = f2b(gelu_g(a1[nt][r]));
            }
        __syncthreads();
        #pragma unroll
        for (int ks = 0; ks < 2; ++ks) {
            bf16x8 aW = *(const bf16x8*)(w1h + (size_t)(wid * 16 + lo) * 256 + is * 64 + ks * 32 + 8 * lg);
            #pragma unroll
            for (int nt = 0; nt < 4; ++nt) {
                bf16x8 bG = *(const bf16x8*)&sG[bi][nt * 16 + lo][ks * 32 + 8 * lg];
                MFMA16(yac[nt], aW, bG);
            }
        }
    }

    // P2: scaled error e -> ews (row-major, bf16)
    float coefv = cfb[s * 64 + c];
    #pragma unroll
    for (int nt = 0; nt < 4; ++nt) {
        int t = nt * 16 + lo; int grow = row0 + t;
        float sc = -coefv * lrb[(size_t)grow * 8 + h] * (2.0f / 64.0f);
        ushort4v k4 = *(const ushort4v*)(kbh + (size_t)grow * 512 + h * 64 + wid * 16 + lg * 4);
        ushort4v v4 = *(const ushort4v*)(vb  + (size_t)grow * 512 + h * 64 + wid * 16 + lg * 4);
        ushort4v ev;
        #pragma unroll
        for (int r = 0; r < 4; ++r)
            ev[r] = f2b(sc * (yac[nt][r] + b2f(k4[r]) - b2f(v4[r])));
        *(ushort4v*)(ews + ubase + t * 64 + wid * 16 + lg * 4) = ev;
    }
}

// ---------------- backward: per (s, kslice/8, islab), dbuf LDS, fp32 partials
// eT built in LDS from phase-A register e (XOR-swizzled, no global ewsT)
__global__ __launch_bounds__(256) void k_bwd(
    const unsigned short* __restrict__ uws, const unsigned short* __restrict__ ews,
    const unsigned short* __restrict__ w0fT, const unsigned short* __restrict__ w0N,
    const unsigned short* __restrict__ w1N, const float* __restrict__ nw_g,
    float* __restrict__ pws, float* __restrict__ gnwb)
{
    __shared__ __attribute__((aligned(16))) unsigned short sGT[2][64][72];
    __shared__ __attribute__((aligned(16))) unsigned short sDAT[2][64][72];
    __shared__ __attribute__((aligned(16))) unsigned short sDAN[2][64][68];
    __shared__ __attribute__((aligned(16))) unsigned short sET[2][64][72];   // e^T, XOR-swizzled
    const int tid = threadIdx.x, blk = blockIdx.x;
    const int s = blk >> 5, ksl = (blk >> 2) & 7, is = blk & 3;
    const int h = s & 7;
    const int wid = tid >> 6, lane = tid & 63, lg = lane >> 4, lo = lane & 15;

    f32x4 gw1a[4], gw0a[4];
    #pragma unroll
    for (int nt = 0; nt < 4; ++nt) { gw1a[nt] = (f32x4)0.f; gw0a[nt] = (f32x4)0.f; }
    float gnwp[4] = {0.f, 0.f, 0.f, 0.f};

    const unsigned short* w0fh = w0fT + h * 16384;
    const unsigned short* w0nh = w0N  + h * 16384;
    const unsigned short* w1nh = w1N  + h * 16384;
    const int tcol = wid * 16 + lo;           // token owned by this thread's e rows

    for (int tt = 0; tt < 8; ++tt) {
        const int bi = tt & 1;
        const int chunk = ksl * 8 + tt;
        const size_t base = (size_t)(s * 64 + chunk) * 4096;

        // ======== phase A: global loads + GEMM1/gelu + dg/da -> LDS[bi] =====
        unsigned short utg[16];
        #pragma unroll
        for (int ks = 0; ks < 2; ++ks)
            #pragma unroll
            for (int jj = 0; jj < 8; ++jj)
                utg[ks * 8 + jj] = uws[base + (size_t)(ks * 32 + 8 * lg + jj) * 64 + wid * 16 + lo];
        ushort4v u4n[4];
        #pragma unroll
        for (int nt = 0; nt < 4; ++nt)
            u4n[nt] = *(const ushort4v*)(uws + base + (size_t)(nt * 16 + lo) * 64 + wid * 16 + lg * 4);

        // GEMM1 recompute: a = u @ w0f
        f32x4 a1[4];
        #pragma unroll
        for (int nt = 0; nt < 4; ++nt) a1[nt] = (f32x4)0.f;
        bf16x8 aF0 = *(const bf16x8*)(uws + base + (size_t)(wid * 16 + lo) * 64 + 8 * lg);
        bf16x8 aF1 = *(const bf16x8*)(uws + base + (size_t)(wid * 16 + lo) * 64 + 32 + 8 * lg);
        #pragma unroll
        for (int nt = 0; nt < 4; ++nt) {
            bf16x8 b0 = *(const bf16x8*)(w0fh + (size_t)(is * 64 + nt * 16 + lo) * 64 + 8 * lg);
            bf16x8 b1 = *(const bf16x8*)(w0fh + (size_t)(is * 64 + nt * 16 + lo) * 64 + 32 + 8 * lg);
            MFMA16(a1[nt], aF0, b0);
            MFMA16(a1[nt], aF1, b1);
        }
        float gpv[4][4];
        #pragma unroll
        for (int nt = 0; nt < 4; ++nt) {
            ushort4v gv;
            #pragma unroll
            for (int r = 0; r < 4; ++r) {
                float g, gp; gelu_both(a1[nt][r], g, gp);
                gv[r] = f2b(g); gpv[nt][r] = gp;
            }
            *(ushort4v*)&sGT[bi][nt * 16 + lo][wid * 16 + lg * 4] = gv;
        }

        // dg = e @ w1^T ; da = dg * gelu'
        f32x4 dga[4];
        #pragma unroll
        for (int nt = 0; nt < 4; ++nt) dga[nt] = (f32x4)0.f;
        bf16x8 eF0 = *(const bf16x8*)(ews + base + (size_t)(wid * 16 + lo) * 64 + 8 * lg);
        bf16x8 eF1 = *(const bf16x8*)(ews + base + (size_t)(wid * 16 + lo) * 64 + 32 + 8 * lg);
        #pragma unroll
        for (int nt = 0; nt < 4; ++nt) {
            bf16x8 b0 = *(const bf16x8*)(w1nh + (size_t)(is * 64 + nt * 16 + lo) * 64 + 8 * lg);
            bf16x8 b1 = *(const bf16x8*)(w1nh + (size_t)(is * 64 + nt * 16 + lo) * 64 + 32 + 8 * lg);
            MFMA16(dga[nt], eF0, b0);
            MFMA16(dga[nt], eF1, b1);
        }
        // scatter e -> sET[bi] (swizzled transpose; this block's 64x64 e tile)
        // element (j,t) stored at sET[j][t ^ (((j>>3)&3)<<3)]; here (j>>3)&3 == lg
        {
            const unsigned short* ep0 = (const unsigned short*)&eF0;
            const unsigned short* ep1 = (const unsigned short*)&eF1;
            const int sw = lg << 3;
            const int tsw = tcol ^ sw;
            #pragma unroll
            for (int jj = 0; jj < 8; ++jj) {
                sET[bi][8 * lg + jj][tsw]      = ep0[jj];
                sET[bi][32 + 8 * lg + jj][tsw] = ep1[jj];
            }
        }
        #pragma unroll
        for (int nt = 0; nt < 4; ++nt) {
            ushort4v dv;
            #pragma unroll
            for (int r = 0; r < 4; ++r) dv[r] = f2b(dga[nt][r] * gpv[nt][r]);
            *(ushort4v*)&sDAT[bi][nt * 16 + lo][wid * 16 + lg * 4] = dv;
            #pragma unroll
            for (int r = 0; r < 4; ++r) sDAN[bi][wid * 16 + lg * 4 + r][nt * 16 + lo] = dv[r];
        }
        __syncthreads();   // single barrier per iter (dbuf protects cross-iter)

        // ======== phase B: gradient GEMMs from LDS[bi] ======================
        // gw1 += g^T e  (A: sGT rows; B: sET rows, swizzle-decoded)
        #pragma unroll
        for (int ks = 0; ks < 2; ++ks) {
            bf16x8 aG = *(const bf16x8*)&sGT[bi][wid * 16 + lo][ks * 32 + 8 * lg];
            #pragma unroll
            for (int nt = 0; nt < 4; ++nt) {
                const int jr = nt * 16 + lo;
                const int swr = ((jr >> 3) & 3) << 3;
                bf16x8 bE = *(const bf16x8*)&sET[bi][jr][(ks * 32 + 8 * lg) ^ swr];
                MFMA16(gw1a[nt], aG, bE);
            }
        }
        #pragma unroll
        for (int ks = 0; ks < 2; ++ks) {
            union { ushort8v u; bf16x8 b; } cu;
            #pragma unroll
            for (int jj = 0; jj < 8; ++jj) cu.u[jj] = utg[ks * 8 + jj];
            #pragma unroll
            for (int nt = 0; nt < 4; ++nt) {
                bf16x8 bD = *(const bf16x8*)&sDAT[bi][nt * 16 + lo][ks * 32 + 8 * lg];
                MFMA16(gw0a[nt], cu.b, bD);
            }
        }
        f32x4 dht[4];
        #pragma unroll
        for (int nt = 0; nt < 4; ++nt) dht[nt] = (f32x4)0.f;
        #pragma unroll
        for (int ks = 0; ks < 2; ++ks) {
            bf16x8 aW0 = *(const bf16x8*)(w0nh + (size_t)(wid * 16 + lo) * 256 + is * 64 + ks * 32 + 8 * lg);
            #pragma unroll
            for (int nt = 0; nt < 4; ++nt) {
                bf16x8 bDA = *(const bf16x8*)&sDAN[bi][nt * 16 + lo][ks * 32 + 8 * lg];
                MFMA16(dht[nt], aW0, bDA);
            }
        }
        #pragma unroll
        for (int nt = 0; nt < 4; ++nt)
            #pragma unroll
            for (int r = 0; r < 4; ++r)
                gnwp[r] += b2f(u4n[nt][r]) * dht[nt][r];
    }

    // epilogue: fp32 partials (record = 8192: gw1 4096 + gw0 4096); gnw fp32
    size_t pb = (size_t)blk * 8192;
    #pragma unroll
    for (int nt = 0; nt < 4; ++nt)
        #pragma unroll
        for (int r = 0; r < 4; ++r)
            pws[pb + (size_t)(wid * 16 + lg * 4 + r) * 64 + nt * 16 + lo] = gw1a[nt][r];
    #pragma unroll
    for (int r = 0; r < 4; ++r) {
        float nwv = nw_g[h * 64 + wid * 16 + lg * 4 + r];
        #pragma unroll
        for (int nt = 0; nt < 4; ++nt)
            pws[pb + 4096 + (size_t)(wid * 16 + lg * 4 + r) * 64 + nt * 16 + lo] = nwv * gw0a[nt][r];
    }
    #pragma unroll
    for (int r = 0; r < 4; ++r) {
        #pragma unroll
        for (int o = 1; o < 16; o <<= 1) gnwp[r] += __shfl_xor(gnwp[r], o);
    }
    if (lo == 0) {
        #pragma unroll
        for (int r = 0; r < 4; ++r)
            gnwb[(size_t)blk * 64 + wid * 16 + lg * 4 + r] = gnwp[r];
    }
}

// ---------------- final reduce: out = A*param0 + sum of partials -----------
__global__ __launch_bounds__(256) void k_reduce(
    const float* __restrict__ pws, const float* __restrict__ gnwb,
    const float* __restrict__ Ab,
    const float* __restrict__ nw_g, const float* __restrict__ w0_g,
    const float* __restrict__ w1_g, float* __restrict__ out)
{
    int gid = blockIdx.x * 256 + threadIdx.x;
    if (gid >= 16 * 32832) return;
    int s = gid / 32832, r = gid % 32832;
    int h = s & 7;
    float A = Ab[s];
    float val;
    if (r < 64) {
        val = A * nw_g[h * 64 + r];
        #pragma unroll
        for (int ks = 0; ks < 8; ++ks)
            #pragma unroll
            for (int i2 = 0; i2 < 4; ++i2)
                val += gnwb[(size_t)(s * 32 + ks * 4 + i2) * 64 + r];
    } else if (r < 16448) {
        int rr = r - 64; int d = rr >> 8; int i = rr & 255; int i2 = i >> 6, iloc = i & 63;
        val = A * w0_g[h * 16384 + rr];
        #pragma unroll
        for (int ks = 0; ks < 8; ++ks)
            val += pws[(size_t)(s * 32 + ks * 4 + i2) * 8192 + 4096 + d * 64 + iloc];
    } else {
        int rr = r - 16448; int i = rr >> 6; int j = rr & 63; int i2 = i >> 6, iloc = i & 63;
        val = A * w1_g[h * 16384 + rr];
        #pragma unroll
        for (int ks = 0; ks < 8; ++ks)
            val += pws[(size_t)(s * 32 + ks * 4 + i2) * 8192 + iloc * 64 + j];
    }
    out[gid] = val;
}

// ---------------- launcher -------------------------------------------------
extern "C" void kernel_launch(void* const* d_in, const int* in_sizes, int n_in,
                              void* d_out, int out_size, void* d_ws, size_t ws_size,
                              hipStream_t stream) {
    (void)in_sizes; (void)n_in; (void)out_size; (void)ws_size;
    const float* seq   = (const float*)d_in[0];
    const float* snw   = (const float*)d_in[1];
    const float* Wk    = (const float*)d_in[2];
    const float* Wv    = (const float*)d_in[3];
    const float* Wstep = (const float*)d_in[4];
    const float* bstep = (const float*)d_in[5];
    const float* Wmom  = (const float*)d_in[6];
    const float* bmom  = (const float*)d_in[7];
    const float* Wdec  = (const float*)d_in[8];
    const float* bdec  = (const float*)d_in[9];
    const float* nw_g  = (const float*)d_in[10];
    const float* w0_g  = (const float*)d_in[11];
    const float* w1_g  = (const float*)d_in[12];
    float* out = (float*)d_out;

    // workspace layout (max offset 35,930,112 B — ewsT eliminated)
    char* ws = (char*)d_ws;
    unsigned short* xb   = (unsigned short*)(ws + 0);          //  8,388,608  dead after k_proj
    unsigned short* uws  = (unsigned short*)(ws + 0);          //  8,388,608  alias xb; k_fwd -> k_bwd
    unsigned short* WkvT = (unsigned short*)(ws + 8388608);    //  1,048,576  dead after k_proj
    float*          gnwb = (float*)        (ws + 8388608);     //    131,072  alias WkvT; k_bwd -> k_reduce
    unsigned short* kbh  = (unsigned short*)(ws + 9437184);    //  8,388,608  dead after k_fwd
    unsigned short* vb   = (unsigned short*)(ws + 17825792);   //  8,388,608  dead after k_fwd
    float*          pws  = (float*)        (ws + 9437184);     // 16,777,216  fp32, alias kbh+vb
    unsigned short* ews  = (unsigned short*)(ws + 26214400);   //  8,388,608
    unsigned short* w0fT = (unsigned short*)(ws + 34603008);   //    262,144
    unsigned short* w1T  = (unsigned short*)(ws + 34865152);   //    262,144
    unsigned short* w0N  = (unsigned short*)(ws + 35127296);   //    262,144
    unsigned short* w1N  = (unsigned short*)(ws + 35389440);   //    262,144
    float* lrb  = (float*)(ws + 35651584);                     //    262,144
    float* momb = (float*)(ws + 35913728);                     //      4,096
    float* decb = (float*)(ws + 35917824);                     //      4,096
    float* cfb  = (float*)(ws + 35921920);                     //      4,096
    float* Ab   = (float*)(ws + 35926016);                     //         64

    k_wprep    <<<320, 256, 0, stream>>>(Wk, Wv, w0_g, w1_g, nw_g, WkvT, w0fT, w1T, w0N, w1N);
    k_rms_lr   <<<2048, 256, 0, stream>>>(seq, snw, Wstep, bstep, xb, lrb);
    k_poolgates<<<128, 256, 0, stream>>>(xb, Wmom, bmom, Wdec, bdec, momb, decb);
    k_proj     <<<512, 256, 0, stream>>>(xb, WkvT, kbh, vb);
    k_coeff    <<<1, 64, 0, stream>>>(momb, decb, cfb, Ab);
    k_fwd      <<<1024, 256, 0, stream>>>(kbh, vb, lrb, cfb, w0fT, w1T, uws, ews);
    k_bwd      <<<512, 256, 0, stream>>>(uws, ews, w0fT, w0N, w1N, nw_g, pws, gnwb);
    k_reduce   <<<2052, 256, 0, stream>>>(pws, gnwb, Ab, nw_g, w0_g, w1_g, out);
}

// Round 15
// 123.463 us; speedup vs baseline: 1.1998x; 1.0746x over previous
//
#include <hip/hip_runtime.h>
#include <math.h>

// ---------------- types ----------------
typedef __attribute__((ext_vector_type(8)))  __bf16 bf16x8;
typedef __attribute__((ext_vector_type(4)))  float  f32x4;
typedef __attribute__((ext_vector_type(4)))  unsigned short ushort4v;
typedef __attribute__((ext_vector_type(8)))  unsigned short ushort8v;

#define MFMA16(acc, a, b) acc = __builtin_amdgcn_mfma_f32_16x16x32_bf16((a),(b),(acc),0,0,0)

__device__ inline unsigned short f2b(float f) {
    __bf16 b = (__bf16)f;                      // native RNE cvt (single op)
    union { __bf16 b; unsigned short u; } v; v.b = b;
    return v.u;
}
__device__ inline float b2f(unsigned short h) {
    union { unsigned int u; float f; } v; v.u = ((unsigned int)h) << 16;
    return v.f;
}
__device__ inline float fast_rcp(float x) { return __builtin_amdgcn_rcpf(x); }
__device__ inline float tanh_fast(float z) {
    float e = __expf(2.0f * z);
    return 1.0f - 2.0f * fast_rcp(e + 1.0f);   // rcp instead of precise div
}
__device__ inline float gelu_g(float x) {
    const float c0 = 0.7978845608028654f, c1 = 0.044715f;
    float z = c0 * x * (1.0f + c1 * x * x);
    return 0.5f * x * (1.0f + tanh_fast(z));
}
__device__ inline void gelu_both(float x, float& g, float& gp) {
    const float c0 = 0.7978845608028654f, c1 = 0.044715f;
    float x2 = x * x;
    float z  = c0 * x * (1.0f + c1 * x2);
    float t  = tanh_fast(z);
    g  = 0.5f * x * (1.0f + t);
    float dz = c0 * (1.0f + 3.0f * c1 * x2);
    gp = 0.5f * (1.0f + t) + 0.5f * x * (1.0f - t * t) * dz;
}
__device__ inline float sigmoidf(float x) { return fast_rcp(1.0f + __expf(-x)); }

// ---------------- weight prep: bf16 converts + transposes ----------------
__global__ __launch_bounds__(256) void k_wprep(
    const float* __restrict__ Wk, const float* __restrict__ Wv,
    const float* __restrict__ w0_g, const float* __restrict__ w1_g,
    const float* __restrict__ nw_g,
    unsigned short* __restrict__ WkvT, unsigned short* __restrict__ w0fT,
    unsigned short* __restrict__ w1T, unsigned short* __restrict__ w0N,
    unsigned short* __restrict__ w1N)
{
    const int bid = blockIdx.x, tid = threadIdx.x;
    __shared__ float tile[64][65];
    if (bid < 128) {
        int kt = bid >> 4, nt = bid & 15;
        const float* src = (nt < 8) ? Wk : Wv;
        int ncol0 = (nt & 7) * 64;
        for (int ii = 0; ii < 16; ++ii) {
            int idx = tid + ii * 256; int r = idx >> 6, cc = idx & 63;
            tile[r][cc] = src[(size_t)(kt * 64 + r) * 512 + ncol0 + cc];
        }
        __syncthreads();
        for (int ii = 0; ii < 16; ++ii) {
            int idx = tid + ii * 256; int r = idx >> 6, cc = idx & 63;
            WkvT[(size_t)(nt * 64 + r) * 512 + kt * 64 + cc] = f2b(tile[cc][r]);
        }
    } else if (bid < 160) {
        int q = bid - 128; int hh = q >> 2, it = q & 3;
        const float* w0h = w0_g + hh * 16384;
        for (int ii = 0; ii < 16; ++ii) {
            int idx = tid + ii * 256; int r = idx >> 6, cc = idx & 63;
            tile[r][cc] = w0h[r * 256 + it * 64 + cc];
        }
        __syncthreads();
        for (int ii = 0; ii < 16; ++ii) {
            int idx = tid + ii * 256; int r = idx >> 6, cc = idx & 63;
            w0fT[hh * 16384 + (it * 64 + r) * 64 + cc] = f2b(nw_g[hh * 64 + cc] * tile[cc][r]);
        }
    } else if (bid < 192) {
        int q = bid - 160; int hh = q >> 2, it = q & 3;
        const float* w1h = w1_g + hh * 16384;
        for (int ii = 0; ii < 16; ++ii) {
            int idx = tid + ii * 256; int r = idx >> 6, cc = idx & 63;
            tile[r][cc] = w1h[(it * 64 + r) * 64 + cc];
        }
        __syncthreads();
        for (int ii = 0; ii < 16; ++ii) {
            int idx = tid + ii * 256; int r = idx >> 6, cc = idx & 63;
            w1T[hh * 16384 + r * 256 + it * 64 + cc] = f2b(tile[cc][r]);
        }
    } else {
        int q = bid - 192;
        int gid = q * 2048 + tid * 8;
        const float* s; unsigned short* d;
        if (gid < 131072) { s = w0_g + gid; d = w0N + gid; }
        else              { s = w1_g + (gid - 131072); d = w1N + (gid - 131072); }
        #pragma unroll
        for (int jj = 0; jj < 8; ++jj) d[jj] = f2b(s[jj]);
    }
}

// ---------------- rmsnorm(seq)->xb(bf16)  +  lr projection (fused) --------
__global__ __launch_bounds__(256) void k_rms_lr(
    const float* __restrict__ seq, const float* __restrict__ wnorm,
    const float* __restrict__ Wstep, const float* __restrict__ bstep,
    unsigned short* __restrict__ xb, float* __restrict__ lrb)
{
    const int wid = threadIdx.x >> 6, lane = threadIdx.x & 63;
    const int t = blockIdx.x * 4 + wid;
    const float* row = seq + (size_t)t * 512 + lane * 8;
    float v[8];
    *(f32x4*)&v[0] = *(const f32x4*)row;
    *(f32x4*)&v[4] = *(const f32x4*)(row + 4);
    float ss = 0.f;
    #pragma unroll
    for (int j = 0; j < 8; ++j) ss += v[j] * v[j];
    #pragma unroll
    for (int o = 1; o < 64; o <<= 1) ss += __shfl_xor(ss, o);
    float rr = rsqrtf(ss * (1.0f / 512.0f) + 1e-6f);
    const float* wn = wnorm + lane * 8;
    ushort8v xs;
    float acc[8] = {0.f,0.f,0.f,0.f,0.f,0.f,0.f,0.f};
    #pragma unroll
    for (int j = 0; j < 8; ++j) {
        float xf = v[j] * rr * wn[j];
        xs[j] = f2b(xf);
        const float* wrow = Wstep + (size_t)(lane * 8 + j) * 8;
        #pragma unroll
        for (int h = 0; h < 8; ++h) acc[h] = fmaf(xf, wrow[h], acc[h]);
    }
    *(ushort8v*)(xb + (size_t)t * 512 + lane * 8) = xs;
    #pragma unroll
    for (int h = 0; h < 8; ++h) {
        #pragma unroll
        for (int o = 1; o < 64; o <<= 1) acc[h] += __shfl_xor(acc[h], o);
    }
    if (lane == 0) {
        #pragma unroll
        for (int h = 0; h < 8; ++h) lrb[(size_t)t * 8 + h] = sigmoidf(acc[h] + bstep[h]);
    }
}

// ---------------- chunk pooling + mom/dec gates (fused) ---------------------
__global__ __launch_bounds__(256) void k_poolgates(
    const unsigned short* __restrict__ xb,
    const float* __restrict__ Wmom, const float* __restrict__ bmom,
    const float* __restrict__ Wdec, const float* __restrict__ bdec,
    float* __restrict__ momout, float* __restrict__ decout)
{
    __shared__ float sP[4][512];
    __shared__ float pooled[512];
    const int bc = blockIdx.x, tid = threadIdx.x;
    const int q = tid >> 6, lane = tid & 63, d0 = lane * 8;
    float p[8] = {0.f,0.f,0.f,0.f,0.f,0.f,0.f,0.f};
    for (int tt = 0; tt < 16; ++tt) {
        int t = q * 16 + tt;
        ushort8v v = *(const ushort8v*)(xb + (size_t)(bc * 64 + t) * 512 + d0);
        #pragma unroll
        for (int j = 0; j < 8; ++j) p[j] += b2f(v[j]);
    }
    #pragma unroll
    for (int j = 0; j < 8; ++j) sP[q][d0 + j] = p[j];
    __syncthreads();
    #pragma unroll
    for (int half = 0; half < 2; ++half) {
        int d = tid + half * 256;
        pooled[d] = (sP[0][d] + sP[1][d] + sP[2][d] + sP[3][d]) * (1.0f / 64.0f);
    }
    __syncthreads();
    if (tid < 64) {
        const int h = tid & 7, dd0 = tid >> 3;
        float pm = 0.f, pd = 0.f;
        #pragma unroll 8
        for (int it = 0; it < 64; ++it) {
            int d = dd0 + it * 8; float pv = pooled[d];
            pm = fmaf(pv, Wmom[d * 8 + h], pm);
            pd = fmaf(pv, Wdec[d * 8 + h], pd);
        }
        #pragma unroll
        for (int o = 8; o < 64; o <<= 1) { pm += __shfl_xor(pm, o); pd += __shfl_xor(pd, o); }
        if (tid < 8) {
            momout[(size_t)bc * 8 + h] = sigmoidf(pm + bmom[h]);
            decout[(size_t)bc * 8 + h] = sigmoidf(pd + bdec[h]);
        }
    }
}

// ---------------- k/v projection (MFMA, 128x128 tile) ---------------------
__global__ __launch_bounds__(256) void k_proj(
    const unsigned short* __restrict__ xb, const unsigned short* __restrict__ WkvT,
    unsigned short* __restrict__ kbh, unsigned short* __restrict__ vb)
{
    __shared__ __attribute__((aligned(16))) unsigned short As[128][72];
    __shared__ __attribute__((aligned(16))) unsigned short Bs[128][72];
    const int tid = threadIdx.x;
    const int bm = blockIdx.x >> 3, bn = blockIdx.x & 7;
    const int m0 = bm * 128, n0 = bn * 128;
    const int wid = tid >> 6, lane = tid & 63, lg = lane >> 4, lo = lane & 15;
    const int wm = wid >> 1, wn = wid & 1;
    f32x4 acc[4][4];
    #pragma unroll
    for (int i = 0; i < 4; ++i)
        #pragma unroll
        for (int j = 0; j < 4; ++j) acc[i][j] = (f32x4)0.f;

    for (int k0 = 0; k0 < 512; k0 += 64) {
        #pragma unroll
        for (int ii = 0; ii < 4; ++ii) {
            int e0 = tid * 32 + ii * 8;
            int r = e0 >> 6, c = e0 & 63;
            *(bf16x8*)&As[r][c] = *(const bf16x8*)(xb   + (size_t)(m0 + r) * 512 + k0 + c);
            *(bf16x8*)&Bs[r][c] = *(const bf16x8*)(WkvT + (size_t)(n0 + r) * 512 + k0 + c);
        }
        __syncthreads();
        #pragma unroll
        for (int ks = 0; ks < 2; ++ks) {
            bf16x8 aF[4], bF[4];
            #pragma unroll
            for (int mt = 0; mt < 4; ++mt) aF[mt] = *(const bf16x8*)&As[wm * 64 + mt * 16 + lo][ks * 32 + 8 * lg];
            #pragma unroll
            for (int nt = 0; nt < 4; ++nt) bF[nt] = *(const bf16x8*)&Bs[wn * 64 + nt * 16 + lo][ks * 32 + 8 * lg];
            #pragma unroll
            for (int mt = 0; mt < 4; ++mt)
                #pragma unroll
                for (int nt = 0; nt < 4; ++nt) MFMA16(acc[mt][nt], aF[mt], bF[nt]);
        }
        __syncthreads();
    }
    #pragma unroll
    for (int mt = 0; mt < 4; ++mt)
        #pragma unroll
        for (int nt = 0; nt < 4; ++nt)
            #pragma unroll
            for (int r = 0; r < 4; ++r) {
                int row = m0 + wm * 64 + mt * 16 + lg * 4 + r;
                int col = n0 + wn * 64 + nt * 16 + lo;
                unsigned short val = f2b(acc[mt][nt][r]);
                if (col < 512) kbh[(size_t)row * 512 + col] = val;
                else           vb[(size_t)row * 512 + col - 512] = val;
            }
}

// ---------------- coeff scan (LDS-preloaded gates) --------------------------
__global__ void k_coeff(const float* __restrict__ mom, const float* __restrict__ dec,
                        float* __restrict__ coeff, float* __restrict__ Aout)
{
    __shared__ float sm[1024], sd[1024];
    int tid = threadIdx.x;   // 64 threads
    #pragma unroll
    for (int i = 0; i < 4; ++i) {
        int idx = (tid + i * 64) * 4;
        *(f32x4*)&sm[idx] = *(const f32x4*)&mom[idx];
        *(f32x4*)&sd[idx] = *(const f32x4*)&dec[idx];
    }
    __syncthreads();
    int s = tid;
    if (s >= 16) return;
    int b = s >> 3, h = s & 7;
    float P = 1.f, S = 1.f;
    coeff[s * 64 + 63] = 1.f;
    for (int cc = 62; cc >= 0; --cc) {
        float Dn = 1.f - sd[(b * 64 + cc + 1) * 8 + h];
        float Mn = sm[(b * 64 + cc + 1) * 8 + h];
        P *= Dn;
        S = P + Mn * S;
        coeff[s * 64 + cc] = S;
    }
    float D0 = 1.f - sd[(b * 64) * 8 + h];
    Aout[s] = P * D0;
}

// ---------------- forward pass: u, e  (per stream-chunk) --------------------
// double-buffered sG: one barrier per islab
__global__ __launch_bounds__(256) void k_fwd(
    const unsigned short* __restrict__ kbh, const unsigned short* __restrict__ vb,
    const float* __restrict__ lrb, const float* __restrict__ cfb,
    const unsigned short* __restrict__ w0fT, const unsigned short* __restrict__ w1T,
    unsigned short* __restrict__ uws, unsigned short* __restrict__ ews)
{
    __shared__ __attribute__((aligned(16))) unsigned short sU[64][72];
    __shared__ __attribute__((aligned(16))) unsigned short sG[2][64][72];
    const int tid = threadIdx.x, blk = blockIdx.x;
    const int s = blk >> 6, c = blk & 63;
    const int b = s >> 3, h = s & 7;
    const int row0 = b * 4096 + c * 64;
    const int wid = tid >> 6, lane = tid & 63, lg = lane >> 4, lo = lane & 15;
    const size_t ubase = (size_t)blk * 4096;

    // P0: per-token rmsnorm of k — thread handles row r = tid>>2, 16 cols
    {
        int r = tid >> 2, c0 = (tid & 3) * 16;
        const unsigned short* kr = kbh + (size_t)(row0 + r) * 512 + h * 64 + c0;
        ushort8v k0 = *(const ushort8v*)kr;
        ushort8v k1 = *(const ushort8v*)(kr + 8);
        float kv[16];
        float ss = 0.f;
        #pragma unroll
        for (int j = 0; j < 8; ++j) { kv[j] = b2f(k0[j]); kv[8 + j] = b2f(k1[j]); }
        #pragma unroll
        for (int j = 0; j < 16; ++j) ss += kv[j] * kv[j];
        ss += __shfl_xor(ss, 1);
        ss += __shfl_xor(ss, 2);
        float rr = rsqrtf(ss * (1.0f / 64.0f) + 1e-6f);
        ushort8v u0, u1;
        #pragma unroll
        for (int j = 0; j < 8; ++j) { u0[j] = f2b(kv[j] * rr); u1[j] = f2b(kv[8 + j] * rr); }
        *(ushort8v*)&sU[r][c0]     = u0;
        *(ushort8v*)&sU[r][c0 + 8] = u1;
        *(ushort8v*)(uws + ubase + r * 64 + c0)     = u0;
        *(ushort8v*)(uws + ubase + r * 64 + c0 + 8) = u1;
    }
    __syncthreads();

    const unsigned short* w0h = w0fT + h * 16384;
    const unsigned short* w1h = w1T  + h * 16384;
    bf16x8 aF0 = *(const bf16x8*)&sU[wid * 16 + lo][8 * lg];
    bf16x8 aF1 = *(const bf16x8*)&sU[wid * 16 + lo][32 + 8 * lg];

    f32x4 yac[4];
    #pragma unroll
    for (int nt = 0; nt < 4; ++nt) yac[nt] = (f32x4)0.f;

    for (int is = 0; is < 4; ++is) {
        const int bi = is & 1;
        f32x4 a1[4];
        #pragma unroll
        for (int nt = 0; nt < 4; ++nt) a1[nt] = (f32x4)0.f;
        #pragma unroll
        for (int nt = 0; nt < 4; ++nt) {
            bf16x8 b0 = *(const bf16x8*)(w0h + (size_t)(is * 64 + nt * 16 + lo) * 64 + 8 * lg);
            bf16x8 b1 = *(const bf16x8*)(w0h + (size_t)(is * 64 + nt * 16 + lo) * 64 + 32 + 8 * lg);
            MFMA16(a1[nt], aF0, b0);
            MFMA16(a1[nt], aF1, b1);
        }
        #pragma unroll
        for (int nt = 0; nt < 4; ++nt)
            #pragma unroll
            for (int r = 0; r < 4; ++r) {
                int t = wid * 16 + lg * 4 + r;
                sG[bi][t][nt * 16 + lo] = f2b(gelu_g(a1[nt][r]));
            }
        __syncthreads();
        #pragma unroll
        for (int ks = 0; ks < 2; ++ks) {
            bf16x8 aW = *(const bf16x8*)(w1h + (size_t)(wid * 16 + lo) * 256 + is * 64 + ks * 32 + 8 * lg);
            #pragma unroll
            for (int nt = 0; nt < 4; ++nt) {
                bf16x8 bG = *(const bf16x8*)&sG[bi][nt * 16 + lo][ks * 32 + 8 * lg];
                MFMA16(yac[nt], aW, bG);
            }
        }
    }

    // P2: scaled error e -> ews (row-major, bf16)
    float coefv = cfb[s * 64 + c];
    #pragma unroll
    for (int nt = 0; nt < 4; ++nt) {
        int t = nt * 16 + lo; int grow = row0 + t;
        float sc = -coefv * lrb[(size_t)grow * 8 + h] * (2.0f / 64.0f);
        ushort4v k4 = *(const ushort4v*)(kbh + (size_t)grow * 512 + h * 64 + wid * 16 + lg * 4);
        ushort4v v4 = *(const ushort4v*)(vb  + (size_t)grow * 512 + h * 64 + wid * 16 + lg * 4);
        ushort4v ev;
        #pragma unroll
        for (int r = 0; r < 4; ++r)
            ev[r] = f2b(sc * (yac[nt][r] + b2f(k4[r]) - b2f(v4[r])));
        *(ushort4v*)(ews + ubase + t * 64 + wid * 16 + lg * 4) = ev;
    }
}

// ---------------- backward: per (s, kslice/8, islab), dbuf LDS, fp32 partials
// eT built in LDS from phase-A register e; u-gather loads moved to phase B
// to shorten live ranges (register-tier fix)
__global__ __launch_bounds__(256) void k_bwd(
    const unsigned short* __restrict__ uws, const unsigned short* __restrict__ ews,
    const unsigned short* __restrict__ w0fT, const unsigned short* __restrict__ w0N,
    const unsigned short* __restrict__ w1N, const float* __restrict__ nw_g,
    float* __restrict__ pws, float* __restrict__ gnwb)
{
    __shared__ __attribute__((aligned(16))) unsigned short sGT[2][64][72];
    __shared__ __attribute__((aligned(16))) unsigned short sDAT[2][64][72];
    __shared__ __attribute__((aligned(16))) unsigned short sDAN[2][64][68];
    __shared__ __attribute__((aligned(16))) unsigned short sET[2][64][72];   // e^T, XOR-swizzled
    const int tid = threadIdx.x, blk = blockIdx.x;
    const int s = blk >> 5, ksl = (blk >> 2) & 7, is = blk & 3;
    const int h = s & 7;
    const int wid = tid >> 6, lane = tid & 63, lg = lane >> 4, lo = lane & 15;

    f32x4 gw1a[4], gw0a[4];
    #pragma unroll
    for (int nt = 0; nt < 4; ++nt) { gw1a[nt] = (f32x4)0.f; gw0a[nt] = (f32x4)0.f; }
    float gnwp[4] = {0.f, 0.f, 0.f, 0.f};

    const unsigned short* w0fh = w0fT + h * 16384;
    const unsigned short* w0nh = w0N  + h * 16384;
    const unsigned short* w1nh = w1N  + h * 16384;
    const int tcol = wid * 16 + lo;           // token owned by this thread's e rows

    for (int tt = 0; tt < 8; ++tt) {
        const int bi = tt & 1;
        const int chunk = ksl * 8 + tt;
        const size_t base = (size_t)(s * 64 + chunk) * 4096;

        // ======== phase A: GEMM1/gelu + dg/da + e-scatter -> LDS[bi] ========
        // GEMM1 recompute: a = u @ w0f
        f32x4 a1[4];
        #pragma unroll
        for (int nt = 0; nt < 4; ++nt) a1[nt] = (f32x4)0.f;
        bf16x8 aF0 = *(const bf16x8*)(uws + base + (size_t)(wid * 16 + lo) * 64 + 8 * lg);
        bf16x8 aF1 = *(const bf16x8*)(uws + base + (size_t)(wid * 16 + lo) * 64 + 32 + 8 * lg);
        #pragma unroll
        for (int nt = 0; nt < 4; ++nt) {
            bf16x8 b0 = *(const bf16x8*)(w0fh + (size_t)(is * 64 + nt * 16 + lo) * 64 + 8 * lg);
            bf16x8 b1 = *(const bf16x8*)(w0fh + (size_t)(is * 64 + nt * 16 + lo) * 64 + 32 + 8 * lg);
            MFMA16(a1[nt], aF0, b0);
            MFMA16(a1[nt], aF1, b1);
        }
        float gpv[4][4];
        #pragma unroll
        for (int nt = 0; nt < 4; ++nt) {
            ushort4v gv;
            #pragma unroll
            for (int r = 0; r < 4; ++r) {
                float g, gp; gelu_both(a1[nt][r], g, gp);
                gv[r] = f2b(g); gpv[nt][r] = gp;
            }
            *(ushort4v*)&sGT[bi][nt * 16 + lo][wid * 16 + lg * 4] = gv;
        }

        // dg = e @ w1^T ; da = dg * gelu'
        f32x4 dga[4];
        #pragma unroll
        for (int nt = 0; nt < 4; ++nt) dga[nt] = (f32x4)0.f;
        bf16x8 eF0 = *(const bf16x8*)(ews + base + (size_t)(wid * 16 + lo) * 64 + 8 * lg);
        bf16x8 eF1 = *(const bf16x8*)(ews + base + (size_t)(wid * 16 + lo) * 64 + 32 + 8 * lg);
        #pragma unroll
        for (int nt = 0; nt < 4; ++nt) {
            bf16x8 b0 = *(const bf16x8*)(w1nh + (size_t)(is * 64 + nt * 16 + lo) * 64 + 8 * lg);
            bf16x8 b1 = *(const bf16x8*)(w1nh + (size_t)(is * 64 + nt * 16 + lo) * 64 + 32 + 8 * lg);
            MFMA16(dga[nt], eF0, b0);
            MFMA16(dga[nt], eF1, b1);
        }
        // scatter e -> sET[bi] (swizzled transpose)
        {
            const unsigned short* ep0 = (const unsigned short*)&eF0;
            const unsigned short* ep1 = (const unsigned short*)&eF1;
            const int tsw = tcol ^ (lg << 3);
            #pragma unroll
            for (int jj = 0; jj < 8; ++jj) {
                sET[bi][8 * lg + jj][tsw]      = ep0[jj];
                sET[bi][32 + 8 * lg + jj][tsw] = ep1[jj];
            }
        }
        #pragma unroll
        for (int nt = 0; nt < 4; ++nt) {
            ushort4v dv;
            #pragma unroll
            for (int r = 0; r < 4; ++r) dv[r] = f2b(dga[nt][r] * gpv[nt][r]);
            *(ushort4v*)&sDAT[bi][nt * 16 + lo][wid * 16 + lg * 4] = dv;
            #pragma unroll
            for (int r = 0; r < 4; ++r) sDAN[bi][wid * 16 + lg * 4 + r][nt * 16 + lo] = dv[r];
        }
        __syncthreads();   // single barrier per iter (dbuf protects cross-iter)

        // ======== phase B: issue u loads, then gradient GEMMs ===============
        // u-operands (consumed late in phase B; issued here so their live range
        // does not overlap phase A's temporaries — keeps VGPR <= tier)
        unsigned short utg[16];
        #pragma unroll
        for (int ks = 0; ks < 2; ++ks)
            #pragma unroll
            for (int jj = 0; jj < 8; ++jj)
                utg[ks * 8 + jj] = uws[base + (size_t)(ks * 32 + 8 * lg + jj) * 64 + wid * 16 + lo];
        ushort4v u4n[4];
        #pragma unroll
        for (int nt = 0; nt < 4; ++nt)
            u4n[nt] = *(const ushort4v*)(uws + base + (size_t)(nt * 16 + lo) * 64 + wid * 16 + lg * 4);

        // gw1 += g^T e  (A: sGT rows; B: sET rows, swizzle-decoded)
        #pragma unroll
        for (int ks = 0; ks < 2; ++ks) {
            bf16x8 aG = *(const bf16x8*)&sGT[bi][wid * 16 + lo][ks * 32 + 8 * lg];
            #pragma unroll
            for (int nt = 0; nt < 4; ++nt) {
                const int jr = nt * 16 + lo;
                const int swr = ((jr >> 3) & 3) << 3;
                bf16x8 bE = *(const bf16x8*)&sET[bi][jr][(ks * 32 + 8 * lg) ^ swr];
                MFMA16(gw1a[nt], aG, bE);
            }
        }
        // gw0 += u^T da  (A: utg gathered; B: sDAT rows)
        #pragma unroll
        for (int ks = 0; ks < 2; ++ks) {
            union { ushort8v u; bf16x8 b; } cu;
            #pragma unroll
            for (int jj = 0; jj < 8; ++jj) cu.u[jj] = utg[ks * 8 + jj];
            #pragma unroll
            for (int nt = 0; nt < 4; ++nt) {
                bf16x8 bD = *(const bf16x8*)&sDAT[bi][nt * 16 + lo][ks * 32 + 8 * lg];
                MFMA16(gw0a[nt], cu.b, bD);
            }
        }
        // dhT = w0 @ da^T  (A: w0N global rows; B: sDAN rows)
        f32x4 dht[4];
        #pragma unroll
        for (int nt = 0; nt < 4; ++nt) dht[nt] = (f32x4)0.f;
        #pragma unroll
        for (int ks = 0; ks < 2; ++ks) {
            bf16x8 aW0 = *(const bf16x8*)(w0nh + (size_t)(wid * 16 + lo) * 256 + is * 64 + ks * 32 + 8 * lg);
            #pragma unroll
            for (int nt = 0; nt < 4; ++nt) {
                bf16x8 bDA = *(const bf16x8*)&sDAN[bi][nt * 16 + lo][ks * 32 + 8 * lg];
                MFMA16(dht[nt], aW0, bDA);
            }
        }
        // gnw partial
        #pragma unroll
        for (int nt = 0; nt < 4; ++nt)
            #pragma unroll
            for (int r = 0; r < 4; ++r)
                gnwp[r] += b2f(u4n[nt][r]) * dht[nt][r];
    }

    // epilogue: fp32 partials (record = 8192: gw1 4096 + gw0 4096); gnw fp32
    size_t pb = (size_t)blk * 8192;
    #pragma unroll
    for (int nt = 0; nt < 4; ++nt)
        #pragma unroll
        for (int r = 0; r < 4; ++r)
            pws[pb + (size_t)(wid * 16 + lg * 4 + r) * 64 + nt * 16 + lo] = gw1a[nt][r];
    #pragma unroll
    for (int r = 0; r < 4; ++r) {
        float nwv = nw_g[h * 64 + wid * 16 + lg * 4 + r];
        #pragma unroll
        for (int nt = 0; nt < 4; ++nt)
            pws[pb + 4096 + (size_t)(wid * 16 + lg * 4 + r) * 64 + nt * 16 + lo] = nwv * gw0a[nt][r];
    }
    #pragma unroll
    for (int r = 0; r < 4; ++r) {
        #pragma unroll
        for (int o = 1; o < 16; o <<= 1) gnwp[r] += __shfl_xor(gnwp[r], o);
    }
    if (lo == 0) {
        #pragma unroll
        for (int r = 0; r < 4; ++r)
            gnwb[(size_t)blk * 64 + wid * 16 + lg * 4 + r] = gnwp[r];
    }
}

// ---------------- final reduce: out = A*param0 + sum of partials -----------
__global__ __launch_bounds__(256) void k_reduce(
    const float* __restrict__ pws, const float* __restrict__ gnwb,
    const float* __restrict__ Ab,
    const float* __restrict__ nw_g, const float* __restrict__ w0_g,
    const float* __restrict__ w1_g, float* __restrict__ out)
{
    int gid = blockIdx.x * 256 + threadIdx.x;
    if (gid >= 16 * 32832) return;
    int s = gid / 32832, r = gid % 32832;
    int h = s & 7;
    float A = Ab[s];
    float val;
    if (r < 64) {
        val = A * nw_g[h * 64 + r];
        #pragma unroll
        for (int ks = 0; ks < 8; ++ks)
            #pragma unroll
            for (int i2 = 0; i2 < 4; ++i2)
                val += gnwb[(size_t)(s * 32 + ks * 4 + i2) * 64 + r];
    } else if (r < 16448) {
        int rr = r - 64; int d = rr >> 8; int i = rr & 255; int i2 = i >> 6, iloc = i & 63;
        val = A * w0_g[h * 16384 + rr];
        #pragma unroll
        for (int ks = 0; ks < 8; ++ks)
            val += pws[(size_t)(s * 32 + ks * 4 + i2) * 8192 + 4096 + d * 64 + iloc];
    } else {
        int rr = r - 16448; int i = rr >> 6; int j = rr & 63; int i2 = i >> 6, iloc = i & 63;
        val = A * w1_g[h * 16384 + rr];
        #pragma unroll
        for (int ks = 0; ks < 8; ++ks)
            val += pws[(size_t)(s * 32 + ks * 4 + i2) * 8192 + iloc * 64 + j];
    }
    out[gid] = val;
}

// ---------------- launcher -------------------------------------------------
extern "C" void kernel_launch(void* const* d_in, const int* in_sizes, int n_in,
                              void* d_out, int out_size, void* d_ws, size_t ws_size,
                              hipStream_t stream) {
    (void)in_sizes; (void)n_in; (void)out_size; (void)ws_size;
    const float* seq   = (const float*)d_in[0];
    const float* snw   = (const float*)d_in[1];
    const float* Wk    = (const float*)d_in[2];
    const float* Wv    = (const float*)d_in[3];
    const float* Wstep = (const float*)d_in[4];
    const float* bstep = (const float*)d_in[5];
    const float* Wmom  = (const float*)d_in[6];
    const float* bmom  = (const float*)d_in[7];
    const float* Wdec  = (const float*)d_in[8];
    const float* bdec  = (const float*)d_in[9];
    const float* nw_g  = (const float*)d_in[10];
    const float* w0_g  = (const float*)d_in[11];
    const float* w1_g  = (const float*)d_in[12];
    float* out = (float*)d_out;

    // workspace layout (max offset 35,930,112 B)
    char* ws = (char*)d_ws;
    unsigned short* xb   = (unsigned short*)(ws + 0);          //  8,388,608  dead after k_proj
    unsigned short* uws  = (unsigned short*)(ws + 0);          //  8,388,608  alias xb; k_fwd -> k_bwd
    unsigned short* WkvT = (unsigned short*)(ws + 8388608);    //  1,048,576  dead after k_proj
    float*          gnwb = (float*)        (ws + 8388608);     //    131,072  alias WkvT; k_bwd -> k_reduce
    unsigned short* kbh  = (unsigned short*)(ws + 9437184);    //  8,388,608  dead after k_fwd
    unsigned short* vb   = (unsigned short*)(ws + 17825792);   //  8,388,608  dead after k_fwd
    float*          pws  = (float*)        (ws + 9437184);     // 16,777,216  fp32, alias kbh+vb
    unsigned short* ews  = (unsigned short*)(ws + 26214400);   //  8,388,608
    unsigned short* w0fT = (unsigned short*)(ws + 34603008);   //    262,144
    unsigned short* w1T  = (unsigned short*)(ws + 34865152);   //    262,144
    unsigned short* w0N  = (unsigned short*)(ws + 35127296);   //    262,144
    unsigned short* w1N  = (unsigned short*)(ws + 35389440);   //    262,144
    float* lrb  = (float*)(ws + 35651584);                     //    262,144
    float* momb = (float*)(ws + 35913728);                     //      4,096
    float* decb = (float*)(ws + 35917824);                     //      4,096
    float* cfb  = (float*)(ws + 35921920);                     //      4,096
    float* Ab   = (float*)(ws + 35926016);                     //         64

    k_wprep    <<<320, 256, 0, stream>>>(Wk, Wv, w0_g, w1_g, nw_g, WkvT, w0fT, w1T, w0N, w1N);
    k_rms_lr   <<<2048, 256, 0, stream>>>(seq, snw, Wstep, bstep, xb, lrb);
    k_poolgates<<<128, 256, 0, stream>>>(xb, Wmom, bmom, Wdec, bdec, momb, decb);
    k_proj     <<<512, 256, 0, stream>>>(xb, WkvT, kbh, vb);
    k_coeff    <<<1, 64, 0, stream>>>(momb, decb, cfb, Ab);
    k_fwd      <<<1024, 256, 0, stream>>>(kbh, vb, lrb, cfb, w0fT, w1T, uws, ews);
    k_bwd      <<<512, 256, 0, stream>>>(uws, ews, w0fT, w0N, w1N, nw_g, pws, gnwb);
    k_reduce   <<<2052, 256, 0, stream>>>(pws, gnwb, Ab, nw_g, w0_g, w1_g, out);
}